// Round 3
// baseline (1634.476 us; speedup 1.0000x reference)
//
#include <hip/hip_runtime.h>

// Problem constants (from reference)
#define F_XC 64
#define F_UC 128
#define F_OUTC 128
#define B_GLOB 512

// Binning parameters: bucket = 32 dest nodes, fixed capacity per bucket.
// E/NB = 3.2M/3125 = 1024 mean edges/bucket, sd~32 (Poisson) -> CAP=1280 is 8 sigma.
#define BUCKET_NODES 32
#define BUCKET_CAP   1280

// ---------------------------------------------------------------------------
// Binning pass: scatter edge records into per-dest-bucket bins.
// 3.2M returning atomics on 3125 cursors (64x fewer fabric atomics than the
// old per-element scatter). Record = {src | dlocal<<17, attr} packed in 8B.
// ---------------------------------------------------------------------------
__global__ __launch_bounds__(256) void reorder_kernel(
    const int* __restrict__ src, const int* __restrict__ dst,
    const float* __restrict__ attr, int* __restrict__ cursors,
    uint2* __restrict__ recs, int E)
{
    int e = blockIdx.x * 256 + threadIdx.x;
    if (e >= E) return;
    int s = src[e];
    int d = dst[e];
    float a = attr[e];
    int b = d >> 5;                 // bucket id
    int pos = atomicAdd(&cursors[b], 1);
    if (pos < BUCKET_CAP) {
        recs[(size_t)b * BUCKET_CAP + pos] =
            make_uint2((unsigned)s | ((unsigned)(d & (BUCKET_NODES - 1)) << 17),
                       __float_as_uint(a));
    }
}

// ---------------------------------------------------------------------------
// Accumulate pass: one block per bucket. LDS tile acc[32][64] accumulated via
// LDS fp32 atomics (ds_add_f32) — no device atomics. Depth-2 software
// pipeline keeps a record load and an x-row load in flight ahead of use.
// Lane f handles feature f: acc[dl][lane] -> consecutive banks, conflict-free.
// ---------------------------------------------------------------------------
__global__ __launch_bounds__(256) void bin_accum_kernel(
    const uint2* __restrict__ recs, const int* __restrict__ cursors,
    const float* __restrict__ x, float* __restrict__ agg, int N)
{
    __shared__ float acc[BUCKET_NODES][F_XC];   // 8 KB
    const int tid = threadIdx.x;
    const int wave = tid >> 6;
    const int lane = tid & 63;

    #pragma unroll
    for (int i = tid; i < BUCKET_NODES * F_XC; i += 256)
        ((float*)acc)[i] = 0.f;
    __syncthreads();

    const int b   = blockIdx.x;
    const int beg = b * BUCKET_CAP;
    int cnt = cursors[b];
    if (cnt > BUCKET_CAP) cnt = BUCKET_CAP;
    const int end = beg + cnt;

    int i = beg + wave;
    if (i < end) {
        // pipelined: rA current, rB next, xA current
        uint2 rA = recs[i];
        int iB = i + 4;
        uint2 rB = recs[iB < end ? iB : beg];
        float xA = x[((rA.x & 0x1FFFF) << 6) + lane];
        while (i < end) {
            int iC = i + 8;
            uint2 rC = recs[iC < end ? iC : beg];
            float xB = x[((rB.x & 0x1FFFF) << 6) + lane];
            atomicAdd(&acc[(rA.x >> 17) & (BUCKET_NODES - 1)][lane],
                      __uint_as_float(rA.y) * xA);
            i += 4;
            rA = rB; rB = rC; xA = xB;
        }
    }
    __syncthreads();

    const int base = b * BUCKET_NODES;
    #pragma unroll
    for (int r = wave; r < BUCKET_NODES; r += 4) {
        int n = base + r;
        if (n < N)
            agg[(size_t)n * F_XC + lane] = acc[r][lane];
    }
}

// ---------------------------------------------------------------------------
// Fallback scatter (old path) if ws_size can't fit the bins.
// ---------------------------------------------------------------------------
__global__ __launch_bounds__(256) void scatter_kernel(
    const int* __restrict__ src, const int* __restrict__ dst,
    const float* __restrict__ attr, const float* __restrict__ x,
    float* __restrict__ agg, int E)
{
    int e = blockIdx.x * 4 + (threadIdx.x >> 6);
    int f = threadIdx.x & 63;
    if (e >= E) return;
    int s = src[e];
    int d = dst[e];
    float a = attr[e];
    float xv = x[(size_t)s * F_XC + f];
    atomicAdd(&agg[(size_t)d * F_XC + f], a * xv);
}

// ---------------------------------------------------------------------------
// Per-batch global projection: UK[b][j] = b_K[j] + sum_k u[b][k]*W_K[64+k][j]
// ---------------------------------------------------------------------------
__global__ __launch_bounds__(128) void global_proj_kernel(
    const float* __restrict__ u, const float* __restrict__ W_K,
    const float* __restrict__ b_K, const float* __restrict__ W_Q,
    const float* __restrict__ b_Q, float* __restrict__ UK,
    float* __restrict__ UQ)
{
    __shared__ float s_u[F_UC];
    int b = blockIdx.x;
    int j = threadIdx.x;
    s_u[j] = u[(size_t)b * F_UC + j];
    __syncthreads();
    float accK = b_K[j];
    float accQ = b_Q[j];
    #pragma unroll 8
    for (int k = 0; k < F_UC; ++k) {
        float uv = s_u[k];
        accK = fmaf(uv, W_K[(size_t)(F_XC + k) * F_OUTC + j], accK);
        accQ = fmaf(uv, W_Q[(size_t)(F_XC + k) * F_OUTC + j], accQ);
    }
    UK[(size_t)b * F_OUTC + j] = accK;
    UQ[(size_t)b * F_OUTC + j] = accQ;
}

// ---------------------------------------------------------------------------
// Output GEMM: K[n][j] = sum_{k<64} agg[n][k]*W_K[k][j] + UK[batch[n]][j]
// 256 thr = 2 nodes x 128 feats; weights in registers; agg row via LDS
// float4 broadcast reads (16x ds_read_b128 instead of 64x ds_read_b32).
// ---------------------------------------------------------------------------
__global__ __launch_bounds__(256) void out_kernel(
    const float* __restrict__ agg, const int* __restrict__ batch,
    const float* __restrict__ W_K, const float* __restrict__ W_Q,
    const float* __restrict__ UK, const float* __restrict__ UQ,
    float* __restrict__ K_out, float* __restrict__ Q_out, int nodes)
{
    const int j = threadIdx.x & 127;
    const int half = threadIdx.x >> 7;

    float wk[F_XC], wq[F_XC];
    #pragma unroll
    for (int k = 0; k < F_XC; ++k) {
        wk[k] = W_K[(size_t)k * F_OUTC + j];
        wq[k] = W_Q[(size_t)k * F_OUTC + j];
    }

    __shared__ float s_agg[2][F_XC];

    for (int base = blockIdx.x * 2; base < nodes; base += gridDim.x * 2) {
        const int n = base + half;
        __syncthreads();   // protect s_agg reads from previous iteration
        if (threadIdx.x < 64) {
            s_agg[0][threadIdx.x] = agg[(size_t)base * F_XC + threadIdx.x];
        } else if (threadIdx.x >= 128 && threadIdx.x < 192) {
            int n1 = base + 1;
            s_agg[1][threadIdx.x - 128] =
                (n1 < nodes) ? agg[(size_t)n1 * F_XC + (threadIdx.x - 128)] : 0.f;
        }
        __syncthreads();
        if (n < nodes) {
            float accK = 0.f, accQ = 0.f;
            const float4* a4p = (const float4*)s_agg[half];
            #pragma unroll
            for (int k4 = 0; k4 < F_XC / 4; ++k4) {
                float4 a4 = a4p[k4];
                accK = fmaf(a4.x, wk[k4 * 4 + 0], accK);
                accQ = fmaf(a4.x, wq[k4 * 4 + 0], accQ);
                accK = fmaf(a4.y, wk[k4 * 4 + 1], accK);
                accQ = fmaf(a4.y, wq[k4 * 4 + 1], accQ);
                accK = fmaf(a4.z, wk[k4 * 4 + 2], accK);
                accQ = fmaf(a4.z, wq[k4 * 4 + 2], accQ);
                accK = fmaf(a4.w, wk[k4 * 4 + 3], accK);
                accQ = fmaf(a4.w, wq[k4 * 4 + 3], accQ);
            }
            const int bb = batch[n];
            K_out[(size_t)n * F_OUTC + j] = accK + UK[(size_t)bb * F_OUTC + j];
            Q_out[(size_t)n * F_OUTC + j] = accQ + UQ[(size_t)bb * F_OUTC + j];
        }
    }
}

// ---------------------------------------------------------------------------
// Launch
// ---------------------------------------------------------------------------
extern "C" void kernel_launch(void* const* d_in, const int* in_sizes, int n_in,
                              void* d_out, int out_size, void* d_ws, size_t ws_size,
                              hipStream_t stream) {
    const float* x         = (const float*)d_in[0];
    const int*   edge_idx  = (const int*)  d_in[1];
    const float* edge_attr = (const float*)d_in[2];
    const float* u         = (const float*)d_in[3];
    const int*   batch     = (const int*)  d_in[4];
    const float* W_K       = (const float*)d_in[5];
    const float* b_K       = (const float*)d_in[6];
    const float* W_Q       = (const float*)d_in[7];
    const float* b_Q       = (const float*)d_in[8];

    const int N = in_sizes[0] / F_XC;       // 100000
    const int E = in_sizes[1] / 2;          // 3200000
    const int NB = (N + BUCKET_NODES - 1) / BUCKET_NODES;   // 3125

    const int* src = edge_idx;
    const int* dst = edge_idx + E;

    float* K_out = (float*)d_out;
    float* Q_out = K_out + (size_t)N * F_OUTC;

    // binned-path workspace: recs | agg | UK | UQ | cursors
    size_t recs_elems = (size_t)NB * BUCKET_CAP;
    size_t need = recs_elems * sizeof(uint2)
                + (size_t)N * F_XC * sizeof(float)
                + 2 * (size_t)B_GLOB * F_OUTC * sizeof(float)
                + (size_t)NB * sizeof(int);

    if (ws_size >= need) {
        uint2* recs   = (uint2*)d_ws;
        float* agg    = (float*)(recs + recs_elems);
        float* UK     = agg + (size_t)N * F_XC;
        float* UQ     = UK + (size_t)B_GLOB * F_OUTC;
        int*   cursors = (int*)(UQ + (size_t)B_GLOB * F_OUTC);

        hipMemsetAsync(cursors, 0, (size_t)NB * sizeof(int), stream);
        reorder_kernel<<<(E + 255) / 256, 256, 0, stream>>>(src, dst, edge_attr,
                                                            cursors, recs, E);
        bin_accum_kernel<<<NB, 256, 0, stream>>>(recs, cursors, x, agg, N);
        global_proj_kernel<<<B_GLOB, 128, 0, stream>>>(u, W_K, b_K, W_Q, b_Q, UK, UQ);
        out_kernel<<<2048, 256, 0, stream>>>(agg, batch, W_K, W_Q, UK, UQ,
                                             K_out, Q_out, N);
    } else {
        // fallback: device-atomic scatter
        float* agg = (float*)d_ws;
        float* UK  = agg + (size_t)N * F_XC;
        float* UQ  = UK + (size_t)B_GLOB * F_OUTC;
        hipMemsetAsync(agg, 0, (size_t)N * F_XC * sizeof(float), stream);
        scatter_kernel<<<(E + 3) / 4, 256, 0, stream>>>(src, dst, edge_attr, x, agg, E);
        global_proj_kernel<<<B_GLOB, 128, 0, stream>>>(u, W_K, b_K, W_Q, b_Q, UK, UQ);
        out_kernel<<<2048, 256, 0, stream>>>(agg, batch, W_K, W_Q, UK, UQ,
                                             K_out, Q_out, N);
    }
}

// Round 4
// 936.220 us; speedup vs baseline: 1.7458x; 1.7458x over previous
//
#include <hip/hip_runtime.h>

// Problem constants (from reference)
#define F_XC 64
#define F_UC 128
#define F_OUTC 128
#define B_GLOB 512

// Fixed-point packing: 2 features per u64 atomic.
// field contribution per edge = rint(term * 2^21) + 2^24  (term = attr*x, |term| < 8)
// Per-dest count <= ~65 (Poisson mean 32) -> field sum < 65*2^24.8 < 2^31. No cross-field carry.
#define FP_SCALE 2097152.0f            // 2^21
#define FP_INV   (1.0f/2097152.0f)
#define FP_BIAS  (1 << 24)

// ---------------------------------------------------------------------------
// Scatter with packed u64 atomics: one wave = 2 edges x 32 feature-pairs.
// Per edge: 32 u64 atomics (vs 64 f32) + 1 count atomic. Fully independent
// waves (round-2 MLP structure) - the x gather hides under the atomic stream.
// ---------------------------------------------------------------------------
__global__ __launch_bounds__(256) void scatter_pack_kernel(
    const int* __restrict__ src, const int* __restrict__ dst,
    const float* __restrict__ attr, const float* __restrict__ x,
    unsigned long long* __restrict__ P, int* __restrict__ cnt, int E)
{
    const int wave = threadIdx.x >> 6;
    const int lane = threadIdx.x & 63;
    const int e2   = lane >> 5;          // which of the wave's 2 edges
    const int fp   = lane & 31;          // feature pair 0..31
    const int e = blockIdx.x * 8 + wave * 2 + e2;
    if (e >= E) return;
    const int s = src[e];
    const int d = dst[e];
    const float a = attr[e];
    const float2 xv = *(const float2*)&x[(size_t)s * F_XC + fp * 2];
    const int i0 = __float2int_rn(a * xv.x * FP_SCALE) + FP_BIAS;   // >= 0
    const int i1 = __float2int_rn(a * xv.y * FP_SCALE) + FP_BIAS;   // >= 0
    const unsigned long long pk =
        ((unsigned long long)(unsigned)i1 << 32) | (unsigned)i0;
    atomicAdd(&P[(size_t)d * 32 + fp], pk);
    if (fp == 0) atomicAdd(&cnt[d], 1);
}

// ---------------------------------------------------------------------------
// Per-batch global projection: UK[b][j] = b_K[j] + sum_k u[b][k]*W_K[64+k][j]
// ---------------------------------------------------------------------------
__global__ __launch_bounds__(128) void global_proj_kernel(
    const float* __restrict__ u, const float* __restrict__ W_K,
    const float* __restrict__ b_K, const float* __restrict__ W_Q,
    const float* __restrict__ b_Q, float* __restrict__ UK,
    float* __restrict__ UQ)
{
    __shared__ float s_u[F_UC];
    int b = blockIdx.x;
    int j = threadIdx.x;
    s_u[j] = u[(size_t)b * F_UC + j];
    __syncthreads();
    float accK = b_K[j];
    float accQ = b_Q[j];
    #pragma unroll 8
    for (int k = 0; k < F_UC; ++k) {
        float uv = s_u[k];
        accK = fmaf(uv, W_K[(size_t)(F_XC + k) * F_OUTC + j], accK);
        accQ = fmaf(uv, W_Q[(size_t)(F_XC + k) * F_OUTC + j], accQ);
    }
    UK[(size_t)b * F_OUTC + j] = accK;
    UQ[(size_t)b * F_OUTC + j] = accQ;
}

// ---------------------------------------------------------------------------
// Output GEMM with fused fixed-point decode.
// 8-node chunks: 256 threads stage+decode 8 rows (256 u64, perfectly
// coalesced, 1 per thread), then 2 nodes x 128 feats in parallel, 4 nodes
// sequential -> 8 concurrent FMA chains, 2 barriers per 8 nodes.
// s_agg reads during compute are wave-broadcast (same address all lanes).
// ---------------------------------------------------------------------------
__global__ __launch_bounds__(256) void out_pack_kernel(
    const unsigned long long* __restrict__ P, const int* __restrict__ cnt,
    const int* __restrict__ batch, const float* __restrict__ W_K,
    const float* __restrict__ W_Q, const float* __restrict__ UK,
    const float* __restrict__ UQ, float* __restrict__ K_out,
    float* __restrict__ Q_out, int N)
{
    const int j = threadIdx.x & 127;
    const int half = threadIdx.x >> 7;
    const int r  = threadIdx.x >> 5;    // staging row 0..7
    const int fp = threadIdx.x & 31;    // staging feature pair

    float wk[F_XC], wq[F_XC];
    #pragma unroll
    for (int k = 0; k < F_XC; ++k) {
        wk[k] = W_K[(size_t)k * F_OUTC + j];
        wq[k] = W_Q[(size_t)k * F_OUTC + j];
    }

    __shared__ float s_agg[8][F_XC];

    for (int chunk = blockIdx.x * 8; chunk < N; chunk += gridDim.x * 8) {
        __syncthreads();   // protect s_agg reads from previous chunk
        int n = chunk + r;
        if (n < N) {
            unsigned long long v = P[(size_t)n * 32 + fp];
            unsigned cb = (unsigned)cnt[n] * (unsigned)FP_BIAS;
            unsigned lo = (unsigned)v;
            unsigned hi = (unsigned)(v >> 32);
            float2 dec;
            dec.x = (float)(int)(lo - cb) * FP_INV;
            dec.y = (float)(int)(hi - cb) * FP_INV;
            *(float2*)&s_agg[r][fp * 2] = dec;
        }
        __syncthreads();
        #pragma unroll
        for (int q = 0; q < 4; ++q) {
            int n2 = chunk + q * 2 + half;
            if (n2 < N) {
                float accK = 0.f, accQ = 0.f;
                const float4* a4p = (const float4*)s_agg[q * 2 + half];
                #pragma unroll
                for (int k4 = 0; k4 < F_XC / 4; ++k4) {
                    float4 a4 = a4p[k4];
                    accK = fmaf(a4.x, wk[k4 * 4 + 0], accK);
                    accQ = fmaf(a4.x, wq[k4 * 4 + 0], accQ);
                    accK = fmaf(a4.y, wk[k4 * 4 + 1], accK);
                    accQ = fmaf(a4.y, wq[k4 * 4 + 1], accQ);
                    accK = fmaf(a4.z, wk[k4 * 4 + 2], accK);
                    accQ = fmaf(a4.z, wq[k4 * 4 + 2], accQ);
                    accK = fmaf(a4.w, wk[k4 * 4 + 3], accK);
                    accQ = fmaf(a4.w, wq[k4 * 4 + 3], accQ);
                }
                const int bb = batch[n2];
                K_out[(size_t)n2 * F_OUTC + j] = accK + UK[(size_t)bb * F_OUTC + j];
                Q_out[(size_t)n2 * F_OUTC + j] = accQ + UQ[(size_t)bb * F_OUTC + j];
            }
        }
    }
}

// ---------------------------------------------------------------------------
// Fallback path (fp32 device-atomic scatter + float-agg out), round-2 code.
// ---------------------------------------------------------------------------
__global__ __launch_bounds__(256) void scatter_kernel(
    const int* __restrict__ src, const int* __restrict__ dst,
    const float* __restrict__ attr, const float* __restrict__ x,
    float* __restrict__ agg, int E)
{
    int e = blockIdx.x * 4 + (threadIdx.x >> 6);
    int f = threadIdx.x & 63;
    if (e >= E) return;
    atomicAdd(&agg[(size_t)dst[e] * F_XC + f],
              attr[e] * x[(size_t)src[e] * F_XC + f]);
}

__global__ __launch_bounds__(256) void out_kernel(
    const float* __restrict__ agg, const int* __restrict__ batch,
    const float* __restrict__ W_K, const float* __restrict__ W_Q,
    const float* __restrict__ UK, const float* __restrict__ UQ,
    float* __restrict__ K_out, float* __restrict__ Q_out, int nodes)
{
    const int j = threadIdx.x & 127;
    const int half = threadIdx.x >> 7;
    float wk[F_XC], wq[F_XC];
    #pragma unroll
    for (int k = 0; k < F_XC; ++k) {
        wk[k] = W_K[(size_t)k * F_OUTC + j];
        wq[k] = W_Q[(size_t)k * F_OUTC + j];
    }
    __shared__ float s_agg[2][F_XC];
    for (int base = blockIdx.x * 2; base < nodes; base += gridDim.x * 2) {
        const int n = base + half;
        __syncthreads();
        if (threadIdx.x < 64) {
            s_agg[0][threadIdx.x] = agg[(size_t)base * F_XC + threadIdx.x];
        } else if (threadIdx.x >= 128 && threadIdx.x < 192) {
            int n1 = base + 1;
            s_agg[1][threadIdx.x - 128] =
                (n1 < nodes) ? agg[(size_t)n1 * F_XC + (threadIdx.x - 128)] : 0.f;
        }
        __syncthreads();
        if (n < nodes) {
            float accK = 0.f, accQ = 0.f;
            #pragma unroll
            for (int k = 0; k < F_XC; ++k) {
                float av = s_agg[half][k];
                accK = fmaf(av, wk[k], accK);
                accQ = fmaf(av, wq[k], accQ);
            }
            const int bb = batch[n];
            K_out[(size_t)n * F_OUTC + j] = accK + UK[(size_t)bb * F_OUTC + j];
            Q_out[(size_t)n * F_OUTC + j] = accQ + UQ[(size_t)bb * F_OUTC + j];
        }
    }
}

// ---------------------------------------------------------------------------
// Launch
// ---------------------------------------------------------------------------
extern "C" void kernel_launch(void* const* d_in, const int* in_sizes, int n_in,
                              void* d_out, int out_size, void* d_ws, size_t ws_size,
                              hipStream_t stream) {
    const float* x         = (const float*)d_in[0];
    const int*   edge_idx  = (const int*)  d_in[1];
    const float* edge_attr = (const float*)d_in[2];
    const float* u         = (const float*)d_in[3];
    const int*   batch     = (const int*)  d_in[4];
    const float* W_K       = (const float*)d_in[5];
    const float* b_K       = (const float*)d_in[6];
    const float* W_Q       = (const float*)d_in[7];
    const float* b_Q       = (const float*)d_in[8];

    const int N = in_sizes[0] / F_XC;       // 100000
    const int E = in_sizes[1] / 2;          // 3200000

    const int* src = edge_idx;
    const int* dst = edge_idx + E;

    float* K_out = (float*)d_out;
    float* Q_out = K_out + (size_t)N * F_OUTC;

    // packed-path workspace: P [N*32 u64] | cnt [N int] | UK | UQ
    size_t need = (size_t)N * 32 * sizeof(unsigned long long)
                + (size_t)N * sizeof(int)
                + 2 * (size_t)B_GLOB * F_OUTC * sizeof(float);

    if (ws_size >= need) {
        unsigned long long* P = (unsigned long long*)d_ws;
        int*   cnt = (int*)(P + (size_t)N * 32);
        float* UK  = (float*)(cnt + N);
        float* UQ  = UK + (size_t)B_GLOB * F_OUTC;

        hipMemsetAsync(P, 0, (size_t)N * 32 * sizeof(unsigned long long), stream);
        hipMemsetAsync(cnt, 0, (size_t)N * sizeof(int), stream);

        scatter_pack_kernel<<<(E + 7) / 8, 256, 0, stream>>>(src, dst, edge_attr,
                                                             x, P, cnt, E);
        global_proj_kernel<<<B_GLOB, 128, 0, stream>>>(u, W_K, b_K, W_Q, b_Q, UK, UQ);
        out_pack_kernel<<<2048, 256, 0, stream>>>(P, cnt, batch, W_K, W_Q, UK, UQ,
                                                  K_out, Q_out, N);
    } else {
        float* agg = (float*)d_ws;
        float* UK  = agg + (size_t)N * F_XC;
        float* UQ  = UK + (size_t)B_GLOB * F_OUTC;
        hipMemsetAsync(agg, 0, (size_t)N * F_XC * sizeof(float), stream);
        scatter_kernel<<<(E + 3) / 4, 256, 0, stream>>>(src, dst, edge_attr, x, agg, E);
        global_proj_kernel<<<B_GLOB, 128, 0, stream>>>(u, W_K, b_K, W_Q, b_Q, UK, UQ);
        out_kernel<<<2048, 256, 0, stream>>>(agg, batch, W_K, W_Q, UK, UQ,
                                             K_out, Q_out, N);
    }
}

// Round 5
// 714.995 us; speedup vs baseline: 2.2860x; 1.3094x over previous
//
#include <hip/hip_runtime.h>

// Problem constants (from reference)
#define F_XC 64
#define F_UC 128
#define F_OUTC 128
#define B_GLOB 512

// ---------------------------------------------------------------------------
// Pass 1: histogram of dest nodes. Small-payload atomics (400 KB counters).
// ---------------------------------------------------------------------------
__global__ __launch_bounds__(256) void hist_kernel(
    const int* __restrict__ dst, int* __restrict__ hist, int E)
{
    int e = blockIdx.x * 256 + threadIdx.x;
    if (e < E) atomicAdd(&hist[dst[e]], 1);
}

// ---------------------------------------------------------------------------
// Pass 2: exclusive scan of hist -> cursors (3 tiny kernels).
// ---------------------------------------------------------------------------
__global__ __launch_bounds__(1024) void scan_block_sums(
    const int* __restrict__ hist, int* __restrict__ partial, int N)
{
    __shared__ int red[1024];
    int i = blockIdx.x * 1024 + threadIdx.x;
    red[threadIdx.x] = (i < N) ? hist[i] : 0;
    __syncthreads();
    for (int s = 512; s > 0; s >>= 1) {
        if (threadIdx.x < s) red[threadIdx.x] += red[threadIdx.x + s];
        __syncthreads();
    }
    if (threadIdx.x == 0) partial[blockIdx.x] = red[0];
}

__global__ __launch_bounds__(128) void scan_partials(int* __restrict__ partial, int nb)
{
    __shared__ int s[128];
    int t = threadIdx.x;
    int v = (t < nb) ? partial[t] : 0;
    s[t] = v;
    __syncthreads();
    for (int off = 1; off < 128; off <<= 1) {
        int a = (t >= off) ? s[t - off] : 0;
        __syncthreads();
        s[t] += a;
        __syncthreads();
    }
    if (t < nb) partial[t] = s[t] - v;   // exclusive
}

__global__ __launch_bounds__(1024) void scan_final(
    const int* __restrict__ hist, const int* __restrict__ partial,
    int* __restrict__ cursors, int N)
{
    __shared__ int s[1024];
    int t = threadIdx.x, i = blockIdx.x * 1024 + t;
    int v = (i < N) ? hist[i] : 0;
    s[t] = v;
    __syncthreads();
    for (int off = 1; off < 1024; off <<= 1) {
        int a = (t >= off) ? s[t - off] : 0;
        __syncthreads();
        s[t] += a;
        __syncthreads();
    }
    if (i < N) cursors[i] = s[t] - v + partial[blockIdx.x];   // exclusive scan
}

// ---------------------------------------------------------------------------
// Pass 3: reorder edges into CSR order. 3.2M small returning atomics on 100k
// cursors (32 per address) + cached 8B record stores (no write-through storm).
// After this kernel cursors[d] == row_end(d); row_beg = cursors[d] - hist[d].
// ---------------------------------------------------------------------------
__global__ __launch_bounds__(256) void reorder_csr(
    const int* __restrict__ src, const int* __restrict__ dst,
    const float* __restrict__ attr, int* __restrict__ cursors,
    uint2* __restrict__ recs, int E)
{
    int e = blockIdx.x * 256 + threadIdx.x;
    if (e >= E) return;
    int pos = atomicAdd(&cursors[dst[e]], 1);
    recs[pos] = make_uint2((unsigned)src[e], __float_as_uint(attr[e]));
}

// ---------------------------------------------------------------------------
// Pass 4: CSR accumulate. One wave per dest node; lane f owns feature f.
// Register accumulation in 4 independent chains; ~32 records per node.
// 100k independent waves -> deep MLP without any payload atomics.
// ---------------------------------------------------------------------------
__global__ __launch_bounds__(256) void csr_accum(
    const uint2* __restrict__ recs, const int* __restrict__ cursors,
    const int* __restrict__ hist, const float* __restrict__ x,
    float* __restrict__ agg, int N)
{
    int node = blockIdx.x * 4 + (threadIdx.x >> 6);
    int lane = threadIdx.x & 63;
    if (node >= N) return;
    int cnt = hist[node];
    int beg = cursors[node] - cnt;

    float a0 = 0.f, a1 = 0.f, a2 = 0.f, a3 = 0.f;
    int k = 0;
    for (; k + 4 <= cnt; k += 4) {
        uint2 r0 = recs[beg + k + 0];
        uint2 r1 = recs[beg + k + 1];
        uint2 r2 = recs[beg + k + 2];
        uint2 r3 = recs[beg + k + 3];
        float x0 = x[(r0.x << 6) + lane];
        float x1 = x[(r1.x << 6) + lane];
        float x2 = x[(r2.x << 6) + lane];
        float x3 = x[(r3.x << 6) + lane];
        a0 = fmaf(__uint_as_float(r0.y), x0, a0);
        a1 = fmaf(__uint_as_float(r1.y), x1, a1);
        a2 = fmaf(__uint_as_float(r2.y), x2, a2);
        a3 = fmaf(__uint_as_float(r3.y), x3, a3);
    }
    for (; k < cnt; ++k) {
        uint2 r = recs[beg + k];
        a0 = fmaf(__uint_as_float(r.y), x[(r.x << 6) + lane], a0);
    }
    agg[(size_t)node * F_XC + lane] = (a0 + a1) + (a2 + a3);
}

// ---------------------------------------------------------------------------
// Per-batch global projection: UK[b][j] = b_K[j] + sum_k u[b][k]*W_K[64+k][j]
// ---------------------------------------------------------------------------
__global__ __launch_bounds__(128) void global_proj_kernel(
    const float* __restrict__ u, const float* __restrict__ W_K,
    const float* __restrict__ b_K, const float* __restrict__ W_Q,
    const float* __restrict__ b_Q, float* __restrict__ UK,
    float* __restrict__ UQ)
{
    __shared__ float s_u[F_UC];
    int b = blockIdx.x;
    int j = threadIdx.x;
    s_u[j] = u[(size_t)b * F_UC + j];
    __syncthreads();
    float accK = b_K[j];
    float accQ = b_Q[j];
    #pragma unroll 8
    for (int k = 0; k < F_UC; ++k) {
        float uv = s_u[k];
        accK = fmaf(uv, W_K[(size_t)(F_XC + k) * F_OUTC + j], accK);
        accQ = fmaf(uv, W_Q[(size_t)(F_XC + k) * F_OUTC + j], accQ);
    }
    UK[(size_t)b * F_OUTC + j] = accK;
    UQ[(size_t)b * F_OUTC + j] = accQ;
}

// ---------------------------------------------------------------------------
// Output GEMM: 32 nodes per block, exactly one chunk per block (no loop).
// 256 threads = 2 nodes x 128 feats in parallel, 16 sequential q-steps.
// Weights in registers; agg rows staged once as float4; LDS reads broadcast.
// ---------------------------------------------------------------------------
__global__ __launch_bounds__(256) void out_csr(
    const float* __restrict__ agg, const int* __restrict__ batch,
    const float* __restrict__ W_K, const float* __restrict__ W_Q,
    const float* __restrict__ UK, const float* __restrict__ UQ,
    float* __restrict__ K_out, float* __restrict__ Q_out, int N)
{
    const int j = threadIdx.x & 127;
    const int half = threadIdx.x >> 7;

    float wk[F_XC], wq[F_XC];
    #pragma unroll
    for (int k = 0; k < F_XC; ++k) {
        wk[k] = W_K[(size_t)k * F_OUTC + j];
        wq[k] = W_Q[(size_t)k * F_OUTC + j];
    }

    __shared__ float s_agg[32][F_XC];   // 8 KB

    const int base = blockIdx.x * 32;
    {   // stage 32 rows (2048 floats) as 512 float4: 2 per thread
        const float4* A4 = (const float4*)(agg + (size_t)base * F_XC);
        float4* S4 = (float4*)s_agg;
        int lim = (N - base) * F_XC / 4;          // guard for ragged tail
        int i0 = threadIdx.x, i1 = threadIdx.x + 256;
        if (i0 < lim) S4[i0] = A4[i0];
        if (i1 < lim) S4[i1] = A4[i1];
    }
    __syncthreads();

    #pragma unroll
    for (int q = 0; q < 16; ++q) {
        int n = base + q * 2 + half;
        if (n < N) {
            float accK = 0.f, accQ = 0.f;
            const float4* a4p = (const float4*)s_agg[q * 2 + half];
            #pragma unroll
            for (int k4 = 0; k4 < F_XC / 4; ++k4) {
                float4 a4 = a4p[k4];
                accK = fmaf(a4.x, wk[k4 * 4 + 0], accK);
                accQ = fmaf(a4.x, wq[k4 * 4 + 0], accQ);
                accK = fmaf(a4.y, wk[k4 * 4 + 1], accK);
                accQ = fmaf(a4.y, wq[k4 * 4 + 1], accQ);
                accK = fmaf(a4.z, wk[k4 * 4 + 2], accK);
                accQ = fmaf(a4.z, wq[k4 * 4 + 2], accQ);
                accK = fmaf(a4.w, wk[k4 * 4 + 3], accK);
                accQ = fmaf(a4.w, wq[k4 * 4 + 3], accQ);
            }
            const int bb = batch[n];
            K_out[(size_t)n * F_OUTC + j] = accK + UK[(size_t)bb * F_OUTC + j];
            Q_out[(size_t)n * F_OUTC + j] = accQ + UQ[(size_t)bb * F_OUTC + j];
        }
    }
}

// ---------------------------------------------------------------------------
// Fallback path (fp32 device-atomic scatter), only if ws is too small.
// ---------------------------------------------------------------------------
__global__ __launch_bounds__(256) void scatter_kernel(
    const int* __restrict__ src, const int* __restrict__ dst,
    const float* __restrict__ attr, const float* __restrict__ x,
    float* __restrict__ agg, int E)
{
    int e = blockIdx.x * 4 + (threadIdx.x >> 6);
    int f = threadIdx.x & 63;
    if (e >= E) return;
    atomicAdd(&agg[(size_t)dst[e] * F_XC + f],
              attr[e] * x[(size_t)src[e] * F_XC + f]);
}

// ---------------------------------------------------------------------------
// Launch
// ---------------------------------------------------------------------------
extern "C" void kernel_launch(void* const* d_in, const int* in_sizes, int n_in,
                              void* d_out, int out_size, void* d_ws, size_t ws_size,
                              hipStream_t stream) {
    const float* x         = (const float*)d_in[0];
    const int*   edge_idx  = (const int*)  d_in[1];
    const float* edge_attr = (const float*)d_in[2];
    const float* u         = (const float*)d_in[3];
    const int*   batch     = (const int*)  d_in[4];
    const float* W_K       = (const float*)d_in[5];
    const float* b_K       = (const float*)d_in[6];
    const float* W_Q       = (const float*)d_in[7];
    const float* b_Q       = (const float*)d_in[8];

    const int N = in_sizes[0] / F_XC;       // 100000
    const int E = in_sizes[1] / 2;          // 3200000

    const int* src = edge_idx;
    const int* dst = edge_idx + E;

    float* K_out = (float*)d_out;
    float* Q_out = K_out + (size_t)N * F_OUTC;

    const int NB1024 = (N + 1023) / 1024;   // scan blocks (98)

    // CSR workspace: recs [E u2] | agg [N*64 f] | hist [N] | cursors [N] |
    //                partial [NB1024] | UK | UQ
    size_t need = (size_t)E * sizeof(uint2)
                + (size_t)N * F_XC * sizeof(float)
                + 2 * (size_t)N * sizeof(int)
                + (size_t)NB1024 * sizeof(int)
                + 2 * (size_t)B_GLOB * F_OUTC * sizeof(float);

    if (ws_size >= need) {
        uint2* recs    = (uint2*)d_ws;
        float* agg     = (float*)(recs + (size_t)E);
        int*   hist    = (int*)(agg + (size_t)N * F_XC);
        int*   cursors = hist + N;
        int*   partial = cursors + N;
        float* UK      = (float*)(partial + NB1024);
        float* UQ      = UK + (size_t)B_GLOB * F_OUTC;

        hipMemsetAsync(hist, 0, (size_t)N * sizeof(int), stream);

        hist_kernel<<<(E + 255) / 256, 256, 0, stream>>>(dst, hist, E);
        scan_block_sums<<<NB1024, 1024, 0, stream>>>(hist, partial, N);
        scan_partials<<<1, 128, 0, stream>>>(partial, NB1024);
        scan_final<<<NB1024, 1024, 0, stream>>>(hist, partial, cursors, N);
        reorder_csr<<<(E + 255) / 256, 256, 0, stream>>>(src, dst, edge_attr,
                                                         cursors, recs, E);
        csr_accum<<<(N + 3) / 4, 256, 0, stream>>>(recs, cursors, hist, x, agg, N);
        global_proj_kernel<<<B_GLOB, 128, 0, stream>>>(u, W_K, b_K, W_Q, b_Q, UK, UQ);
        out_csr<<<(N + 31) / 32, 256, 0, stream>>>(agg, batch, W_K, W_Q, UK, UQ,
                                                   K_out, Q_out, N);
    } else {
        float* agg = (float*)d_ws;
        float* UK  = agg + (size_t)N * F_XC;
        float* UQ  = UK + (size_t)B_GLOB * F_OUTC;
        hipMemsetAsync(agg, 0, (size_t)N * F_XC * sizeof(float), stream);
        scatter_kernel<<<(E + 3) / 4, 256, 0, stream>>>(src, dst, edge_attr, x, agg, E);
        global_proj_kernel<<<B_GLOB, 128, 0, stream>>>(u, W_K, b_K, W_Q, b_Q, UK, UQ);
        out_csr<<<(N + 31) / 32, 256, 0, stream>>>(agg, batch, W_K, W_Q, UK, UQ,
                                                   K_out, Q_out, N);
    }
}

// Round 6
// 669.767 us; speedup vs baseline: 2.4404x; 1.0675x over previous
//
#include <hip/hip_runtime.h>

// Problem constants (from reference)
#define F_XC 64
#define F_UC 128
#define F_OUTC 128
#define B_GLOB 512
#define NXCD 8
#define RCHUNK 2048   // edges scanned per block in reorder

// ---------------------------------------------------------------------------
// Pass 1: histogram of dest nodes. Small-payload atomics (400 KB counters).
// ---------------------------------------------------------------------------
__global__ __launch_bounds__(256) void hist_kernel(
    const int* __restrict__ dst, int* __restrict__ hist, int E)
{
    int e = blockIdx.x * 256 + threadIdx.x;
    if (e < E) atomicAdd(&hist[dst[e]], 1);
}

// ---------------------------------------------------------------------------
// Pass 2: exclusive scan of hist -> cursors (3 tiny kernels).
// ---------------------------------------------------------------------------
__global__ __launch_bounds__(1024) void scan_block_sums(
    const int* __restrict__ hist, int* __restrict__ partial, int N)
{
    __shared__ int red[1024];
    int i = blockIdx.x * 1024 + threadIdx.x;
    red[threadIdx.x] = (i < N) ? hist[i] : 0;
    __syncthreads();
    for (int s = 512; s > 0; s >>= 1) {
        if (threadIdx.x < s) red[threadIdx.x] += red[threadIdx.x + s];
        __syncthreads();
    }
    if (threadIdx.x == 0) partial[blockIdx.x] = red[0];
}

__global__ __launch_bounds__(128) void scan_partials(int* __restrict__ partial, int nb)
{
    __shared__ int s[128];
    int t = threadIdx.x;
    int v = (t < nb) ? partial[t] : 0;
    s[t] = v;
    __syncthreads();
    for (int off = 1; off < 128; off <<= 1) {
        int a = (t >= off) ? s[t - off] : 0;
        __syncthreads();
        s[t] += a;
        __syncthreads();
    }
    if (t < nb) partial[t] = s[t] - v;   // exclusive
}

__global__ __launch_bounds__(1024) void scan_final(
    const int* __restrict__ hist, const int* __restrict__ partial,
    int* __restrict__ cursors, int N)
{
    __shared__ int s[1024];
    int t = threadIdx.x, i = blockIdx.x * 1024 + t;
    int v = (i < N) ? hist[i] : 0;
    s[t] = v;
    __syncthreads();
    for (int off = 1; off < 1024; off <<= 1) {
        int a = (t >= off) ? s[t - off] : 0;
        __syncthreads();
        s[t] += a;
        __syncthreads();
    }
    if (i < N) cursors[i] = s[t] - v + partial[blockIdx.x];   // exclusive scan
}

// ---------------------------------------------------------------------------
// Pass 3: XCD-partitioned reorder. Dest space split into 8 ranges of rsize
// nodes; block (bid&7) owns range (bid&7) and scans edge chunk (bid>>3).
// With round-robin block->XCD dispatch, all writers of any rec cacheline sit
// on one XCD -> lines fill completely in that L2 before eviction (write amp
// ~1 instead of the 8x partial-sector storm measured in round 5).
// Cost: dst[] is read 8x (LLC-served). Correctness never depends on the
// placement heuristic.
// ---------------------------------------------------------------------------
__global__ __launch_bounds__(256) void reorder_xcd(
    const int* __restrict__ src, const int* __restrict__ dst,
    const float* __restrict__ attr, int* __restrict__ cursors,
    uint2* __restrict__ recs, int E, int rsize)
{
    const int range = blockIdx.x & (NXCD - 1);
    const int chunk = blockIdx.x >> 3;
    const int lo = range * rsize;
    const int hi = lo + rsize;
    int base = chunk * RCHUNK + threadIdx.x;
    #pragma unroll
    for (int i = 0; i < RCHUNK / 256; ++i) {
        int e = base + i * 256;
        if (e < E) {
            int d = dst[e];
            if (d >= lo && d < hi) {
                int pos = atomicAdd(&cursors[d], 1);
                recs[pos] = make_uint2((unsigned)src[e], __float_as_uint(attr[e]));
            }
        }
    }
}

// ---------------------------------------------------------------------------
// Pass 4: CSR accumulate. One wave per dest node; lane f owns feature f.
// 8 independent FMA chains / 16 loads in flight per wave (was 4) for MLP.
// ---------------------------------------------------------------------------
__global__ __launch_bounds__(256) void csr_accum(
    const uint2* __restrict__ recs, const int* __restrict__ cursors,
    const int* __restrict__ hist, const float* __restrict__ x,
    float* __restrict__ agg, int N)
{
    int node = blockIdx.x * 4 + (threadIdx.x >> 6);
    int lane = threadIdx.x & 63;
    if (node >= N) return;
    int cnt = hist[node];
    int beg = cursors[node] - cnt;

    float a0 = 0.f, a1 = 0.f, a2 = 0.f, a3 = 0.f;
    float a4 = 0.f, a5 = 0.f, a6 = 0.f, a7 = 0.f;
    int k = 0;
    for (; k + 8 <= cnt; k += 8) {
        uint2 r0 = recs[beg + k + 0];
        uint2 r1 = recs[beg + k + 1];
        uint2 r2 = recs[beg + k + 2];
        uint2 r3 = recs[beg + k + 3];
        uint2 r4 = recs[beg + k + 4];
        uint2 r5 = recs[beg + k + 5];
        uint2 r6 = recs[beg + k + 6];
        uint2 r7 = recs[beg + k + 7];
        float x0 = x[(r0.x << 6) + lane];
        float x1 = x[(r1.x << 6) + lane];
        float x2 = x[(r2.x << 6) + lane];
        float x3 = x[(r3.x << 6) + lane];
        float x4 = x[(r4.x << 6) + lane];
        float x5 = x[(r5.x << 6) + lane];
        float x6 = x[(r6.x << 6) + lane];
        float x7 = x[(r7.x << 6) + lane];
        a0 = fmaf(__uint_as_float(r0.y), x0, a0);
        a1 = fmaf(__uint_as_float(r1.y), x1, a1);
        a2 = fmaf(__uint_as_float(r2.y), x2, a2);
        a3 = fmaf(__uint_as_float(r3.y), x3, a3);
        a4 = fmaf(__uint_as_float(r4.y), x4, a4);
        a5 = fmaf(__uint_as_float(r5.y), x5, a5);
        a6 = fmaf(__uint_as_float(r6.y), x6, a6);
        a7 = fmaf(__uint_as_float(r7.y), x7, a7);
    }
    for (; k < cnt; ++k) {
        uint2 r = recs[beg + k];
        a0 = fmaf(__uint_as_float(r.y), x[(r.x << 6) + lane], a0);
    }
    agg[(size_t)node * F_XC + lane] =
        ((a0 + a1) + (a2 + a3)) + ((a4 + a5) + (a6 + a7));
}

// ---------------------------------------------------------------------------
// Per-batch global projection: UK[b][j] = b_K[j] + sum_k u[b][k]*W_K[64+k][j]
// ---------------------------------------------------------------------------
__global__ __launch_bounds__(128) void global_proj_kernel(
    const float* __restrict__ u, const float* __restrict__ W_K,
    const float* __restrict__ b_K, const float* __restrict__ W_Q,
    const float* __restrict__ b_Q, float* __restrict__ UK,
    float* __restrict__ UQ)
{
    __shared__ float s_u[F_UC];
    int b = blockIdx.x;
    int j = threadIdx.x;
    s_u[j] = u[(size_t)b * F_UC + j];
    __syncthreads();
    float accK = b_K[j];
    float accQ = b_Q[j];
    #pragma unroll 8
    for (int k = 0; k < F_UC; ++k) {
        float uv = s_u[k];
        accK = fmaf(uv, W_K[(size_t)(F_XC + k) * F_OUTC + j], accK);
        accQ = fmaf(uv, W_Q[(size_t)(F_XC + k) * F_OUTC + j], accQ);
    }
    UK[(size_t)b * F_OUTC + j] = accK;
    UQ[(size_t)b * F_OUTC + j] = accQ;
}

// ---------------------------------------------------------------------------
// Output GEMM: 4 chunks of 32 nodes per block (weight regs amortized 4x).
// 256 threads = 2 nodes x 128 feats in parallel, 16 sequential q-steps.
// ---------------------------------------------------------------------------
__global__ __launch_bounds__(256) void out_csr(
    const float* __restrict__ agg, const int* __restrict__ batch,
    const float* __restrict__ W_K, const float* __restrict__ W_Q,
    const float* __restrict__ UK, const float* __restrict__ UQ,
    float* __restrict__ K_out, float* __restrict__ Q_out, int N)
{
    const int j = threadIdx.x & 127;
    const int half = threadIdx.x >> 7;

    float wk[F_XC], wq[F_XC];
    #pragma unroll
    for (int k = 0; k < F_XC; ++k) {
        wk[k] = W_K[(size_t)k * F_OUTC + j];
        wq[k] = W_Q[(size_t)k * F_OUTC + j];
    }

    __shared__ float s_agg[32][F_XC];   // 8 KB

    #pragma unroll
    for (int c = 0; c < 4; ++c) {
        const int base = blockIdx.x * 128 + c * 32;
        if (base >= N) break;
        __syncthreads();   // protect s_agg from previous chunk's readers
        {   // stage 32 rows (2048 floats) as 512 float4: 2 per thread
            const float4* A4 = (const float4*)(agg + (size_t)base * F_XC);
            float4* S4 = (float4*)s_agg;
            int lim = (N - base) * (F_XC / 4);      // ragged-tail guard
            if (lim > 512) lim = 512;
            int i0 = threadIdx.x, i1 = threadIdx.x + 256;
            if (i0 < lim) S4[i0] = A4[i0];
            if (i1 < lim) S4[i1] = A4[i1];
        }
        __syncthreads();

        #pragma unroll
        for (int q = 0; q < 16; ++q) {
            int n = base + q * 2 + half;
            if (n < N) {
                float accK = 0.f, accQ = 0.f;
                const float4* a4p = (const float4*)s_agg[q * 2 + half];
                #pragma unroll
                for (int k4 = 0; k4 < F_XC / 4; ++k4) {
                    float4 a4 = a4p[k4];
                    accK = fmaf(a4.x, wk[k4 * 4 + 0], accK);
                    accQ = fmaf(a4.x, wq[k4 * 4 + 0], accQ);
                    accK = fmaf(a4.y, wk[k4 * 4 + 1], accK);
                    accQ = fmaf(a4.y, wq[k4 * 4 + 1], accQ);
                    accK = fmaf(a4.z, wk[k4 * 4 + 2], accK);
                    accQ = fmaf(a4.z, wq[k4 * 4 + 2], accQ);
                    accK = fmaf(a4.w, wk[k4 * 4 + 3], accK);
                    accQ = fmaf(a4.w, wq[k4 * 4 + 3], accQ);
                }
                const int bb = batch[n];
                K_out[(size_t)n * F_OUTC + j] = accK + UK[(size_t)bb * F_OUTC + j];
                Q_out[(size_t)n * F_OUTC + j] = accQ + UQ[(size_t)bb * F_OUTC + j];
            }
        }
    }
}

// ---------------------------------------------------------------------------
// Fallback path (fp32 device-atomic scatter), only if ws is too small.
// ---------------------------------------------------------------------------
__global__ __launch_bounds__(256) void scatter_kernel(
    const int* __restrict__ src, const int* __restrict__ dst,
    const float* __restrict__ attr, const float* __restrict__ x,
    float* __restrict__ agg, int E)
{
    int e = blockIdx.x * 4 + (threadIdx.x >> 6);
    int f = threadIdx.x & 63;
    if (e >= E) return;
    atomicAdd(&agg[(size_t)dst[e] * F_XC + f],
              attr[e] * x[(size_t)src[e] * F_XC + f]);
}

// ---------------------------------------------------------------------------
// Launch
// ---------------------------------------------------------------------------
extern "C" void kernel_launch(void* const* d_in, const int* in_sizes, int n_in,
                              void* d_out, int out_size, void* d_ws, size_t ws_size,
                              hipStream_t stream) {
    const float* x         = (const float*)d_in[0];
    const int*   edge_idx  = (const int*)  d_in[1];
    const float* edge_attr = (const float*)d_in[2];
    const float* u         = (const float*)d_in[3];
    const int*   batch     = (const int*)  d_in[4];
    const float* W_K       = (const float*)d_in[5];
    const float* b_K       = (const float*)d_in[6];
    const float* W_Q       = (const float*)d_in[7];
    const float* b_Q       = (const float*)d_in[8];

    const int N = in_sizes[0] / F_XC;       // 100000
    const int E = in_sizes[1] / 2;          // 3200000

    const int* src = edge_idx;
    const int* dst = edge_idx + E;

    float* K_out = (float*)d_out;
    float* Q_out = K_out + (size_t)N * F_OUTC;

    const int NB1024 = (N + 1023) / 1024;   // scan blocks (98)
    const int rsize  = (N + NXCD - 1) / NXCD;

    // CSR workspace: recs [E u2] | agg [N*64 f] | hist [N] | cursors [N] |
    //                partial [NB1024] | UK | UQ
    size_t need = (size_t)E * sizeof(uint2)
                + (size_t)N * F_XC * sizeof(float)
                + 2 * (size_t)N * sizeof(int)
                + (size_t)NB1024 * sizeof(int)
                + 2 * (size_t)B_GLOB * F_OUTC * sizeof(float);

    if (ws_size >= need) {
        uint2* recs    = (uint2*)d_ws;
        float* agg     = (float*)(recs + (size_t)E);
        int*   hist    = (int*)(agg + (size_t)N * F_XC);
        int*   cursors = hist + N;
        int*   partial = cursors + N;
        float* UK      = (float*)(partial + NB1024);
        float* UQ      = UK + (size_t)B_GLOB * F_OUTC;

        hipMemsetAsync(hist, 0, (size_t)N * sizeof(int), stream);

        hist_kernel<<<(E + 255) / 256, 256, 0, stream>>>(dst, hist, E);
        scan_block_sums<<<NB1024, 1024, 0, stream>>>(hist, partial, N);
        scan_partials<<<1, 128, 0, stream>>>(partial, NB1024);
        scan_final<<<NB1024, 1024, 0, stream>>>(hist, partial, cursors, N);

        const int nchunks = (E + RCHUNK - 1) / RCHUNK;
        reorder_xcd<<<nchunks * NXCD, 256, 0, stream>>>(src, dst, edge_attr,
                                                        cursors, recs, E, rsize);
        csr_accum<<<(N + 3) / 4, 256, 0, stream>>>(recs, cursors, hist, x, agg, N);
        global_proj_kernel<<<B_GLOB, 128, 0, stream>>>(u, W_K, b_K, W_Q, b_Q, UK, UQ);
        out_csr<<<(N + 127) / 128, 256, 0, stream>>>(agg, batch, W_K, W_Q, UK, UQ,
                                                     K_out, Q_out, N);
    } else {
        float* agg = (float*)d_ws;
        float* UK  = agg + (size_t)N * F_XC;
        float* UQ  = UK + (size_t)B_GLOB * F_OUTC;
        hipMemsetAsync(agg, 0, (size_t)N * F_XC * sizeof(float), stream);
        scatter_kernel<<<(E + 3) / 4, 256, 0, stream>>>(src, dst, edge_attr, x, agg, E);
        global_proj_kernel<<<B_GLOB, 128, 0, stream>>>(u, W_K, b_K, W_Q, b_Q, UK, UQ);
        out_csr<<<(N + 127) / 128, 256, 0, stream>>>(agg, batch, W_K, W_Q, UK, UQ,
                                                     K_out, Q_out, N);
    }
}

// Round 7
// 605.871 us; speedup vs baseline: 2.6977x; 1.1055x over previous
//
#include <hip/hip_runtime.h>

// Problem constants (from reference)
#define F_XC 64
#define F_UC 128
#define F_OUTC 128
#define B_GLOB 512
#define NBUCK 128          // coarse dst-range buckets (pass A/B)

// ---------------------------------------------------------------------------
// Pass 1: histogram of dest nodes. Small-payload atomics (400 KB counters).
// ---------------------------------------------------------------------------
__global__ __launch_bounds__(256) void hist_kernel(
    const int* __restrict__ dst, int* __restrict__ hist, int E)
{
    int e = blockIdx.x * 256 + threadIdx.x;
    if (e < E) atomicAdd(&hist[dst[e]], 1);
}

// ---------------------------------------------------------------------------
// Pass 2: exclusive scan of hist -> cursors (3 tiny kernels).
// cursors[] is NEVER mutated afterwards (pass B uses LDS copies).
// ---------------------------------------------------------------------------
__global__ __launch_bounds__(1024) void scan_block_sums(
    const int* __restrict__ hist, int* __restrict__ partial, int N)
{
    __shared__ int red[1024];
    int i = blockIdx.x * 1024 + threadIdx.x;
    red[threadIdx.x] = (i < N) ? hist[i] : 0;
    __syncthreads();
    for (int s = 512; s > 0; s >>= 1) {
        if (threadIdx.x < s) red[threadIdx.x] += red[threadIdx.x + s];
        __syncthreads();
    }
    if (threadIdx.x == 0) partial[blockIdx.x] = red[0];
}

__global__ __launch_bounds__(128) void scan_partials(int* __restrict__ partial, int nb)
{
    __shared__ int s[128];
    int t = threadIdx.x;
    int v = (t < nb) ? partial[t] : 0;
    s[t] = v;
    __syncthreads();
    for (int off = 1; off < 128; off <<= 1) {
        int a = (t >= off) ? s[t - off] : 0;
        __syncthreads();
        s[t] += a;
        __syncthreads();
    }
    if (t < nb) partial[t] = s[t] - v;   // exclusive
}

__global__ __launch_bounds__(1024) void scan_final(
    const int* __restrict__ hist, const int* __restrict__ partial,
    int* __restrict__ cursors, int N)
{
    __shared__ int s[1024];
    int t = threadIdx.x, i = blockIdx.x * 1024 + t;
    int v = (i < N) ? hist[i] : 0;
    s[t] = v;
    __syncthreads();
    for (int off = 1; off < 1024; off <<= 1) {
        int a = (t >= off) ? s[t - off] : 0;
        __syncthreads();
        s[t] += a;
        __syncthreads();
    }
    if (i < N) cursors[i] = s[t] - v + partial[blockIdx.x];   // exclusive scan
}

// ---------------------------------------------------------------------------
// Init pass-A write cursors: one per coarse bucket, = CSR offset of the
// bucket's first node (bucket regions are contiguous in CSR order).
// ---------------------------------------------------------------------------
__global__ __launch_bounds__(128) void initA_kernel(
    const int* __restrict__ cursors, int* __restrict__ gcurA, int N, int BSZ, int E)
{
    int b = threadIdx.x;
    if (b < NBUCK) {
        long long idx = (long long)b * BSZ;
        gcurA[b] = (idx < N) ? cursors[idx] : E;
    }
}

// ---------------------------------------------------------------------------
// Pass A: coarse partition into NBUCK dst-range buckets.
// Per block: LDS histogram over 4096 edges -> 128 global atomics reserve
// contiguous runs -> grouped writes (avg 4096/128 = 32 recs = 256 B run per
// bucket per block). Record packs src (17b) | dlocal (10b) <<17, attr.
// ---------------------------------------------------------------------------
__global__ __launch_bounds__(256) void partA_kernel(
    const int* __restrict__ src, const int* __restrict__ dst,
    const float* __restrict__ attr, int* __restrict__ gcurA,
    uint2* __restrict__ recsA, int E, int BSZ)
{
    __shared__ int lhist[NBUCK];
    __shared__ int lbase[NBUCK];
    if (threadIdx.x < NBUCK) lhist[threadIdx.x] = 0;
    __syncthreads();

    const int cbase = blockIdx.x * 4096;
    unsigned pk[16];
    float    av[16];
    unsigned meta[16];

    #pragma unroll
    for (int i = 0; i < 16; ++i) {
        int e = cbase + i * 256 + threadIdx.x;
        if (e < E) {
            int d = dst[e];
            int b = d / BSZ;
            int r = atomicAdd(&lhist[b], 1);            // LDS atomic: rank
            pk[i]   = (unsigned)src[e] | ((unsigned)(d - b * BSZ) << 17);
            av[i]   = attr[e];
            meta[i] = (unsigned)b | ((unsigned)r << 8);
        } else {
            meta[i] = 0xFFFFFFFFu;
        }
    }
    __syncthreads();
    if (threadIdx.x < NBUCK)
        lbase[threadIdx.x] = atomicAdd(&gcurA[threadIdx.x], lhist[threadIdx.x]);
    __syncthreads();

    #pragma unroll
    for (int i = 0; i < 16; ++i) {
        if (meta[i] != 0xFFFFFFFFu) {
            int b = meta[i] & 0xFF;
            int r = (int)(meta[i] >> 8);
            recsA[lbase[b] + r] = make_uint2(pk[i], __float_as_uint(av[i]));
        }
    }
}

// ---------------------------------------------------------------------------
// Pass B: fine CSR placement within each bucket. One block per bucket; the
// bucket's node cursors live in LDS (no global atomics, no global cursor
// mutation); the write window is the bucket's ~200-400 KB CSR slice ->
// block-local, L2-resident, full-line evictions.
// ---------------------------------------------------------------------------
__global__ __launch_bounds__(1024) void partB_kernel(
    const uint2* __restrict__ recsA, const int* __restrict__ cursors,
    uint2* __restrict__ recs, int N, int E, int BSZ)
{
    __shared__ int Lcur[1024];            // BSZ <= 1024 for this problem size
    const int b  = blockIdx.x;
    const int lo = b * BSZ;
    const int hi = (lo + BSZ < N) ? lo + BSZ : N;
    const int bsz = hi - lo;
    if ((int)threadIdx.x < bsz) Lcur[threadIdx.x] = cursors[lo + threadIdx.x];
    __syncthreads();

    const int rbeg = cursors[lo];
    const int rend = (hi < N) ? cursors[hi] : E;
    for (int r = rbeg + threadIdx.x; r < rend; r += 1024) {
        uint2 v = recsA[r];
        int dl  = (int)(v.x >> 17);
        int pos = atomicAdd(&Lcur[dl], 1);            // LDS atomic
        recs[pos] = make_uint2(v.x & 0x1FFFFu, v.y);
    }
}

// ---------------------------------------------------------------------------
// Pass 4: CSR accumulate. One wave per dest node; lane f owns feature f.
// 8 independent FMA chains / 16 loads in flight per wave.
// cursors[] is the pristine exclusive scan -> beg = cursors[node].
// ---------------------------------------------------------------------------
__global__ __launch_bounds__(256) void csr_accum(
    const uint2* __restrict__ recs, const int* __restrict__ cursors,
    const int* __restrict__ hist, const float* __restrict__ x,
    float* __restrict__ agg, int N)
{
    int node = blockIdx.x * 4 + (threadIdx.x >> 6);
    int lane = threadIdx.x & 63;
    if (node >= N) return;
    int cnt = hist[node];
    int beg = cursors[node];

    float a0 = 0.f, a1 = 0.f, a2 = 0.f, a3 = 0.f;
    float a4 = 0.f, a5 = 0.f, a6 = 0.f, a7 = 0.f;
    int k = 0;
    for (; k + 8 <= cnt; k += 8) {
        uint2 r0 = recs[beg + k + 0];
        uint2 r1 = recs[beg + k + 1];
        uint2 r2 = recs[beg + k + 2];
        uint2 r3 = recs[beg + k + 3];
        uint2 r4 = recs[beg + k + 4];
        uint2 r5 = recs[beg + k + 5];
        uint2 r6 = recs[beg + k + 6];
        uint2 r7 = recs[beg + k + 7];
        float x0 = x[(r0.x << 6) + lane];
        float x1 = x[(r1.x << 6) + lane];
        float x2 = x[(r2.x << 6) + lane];
        float x3 = x[(r3.x << 6) + lane];
        float x4 = x[(r4.x << 6) + lane];
        float x5 = x[(r5.x << 6) + lane];
        float x6 = x[(r6.x << 6) + lane];
        float x7 = x[(r7.x << 6) + lane];
        a0 = fmaf(__uint_as_float(r0.y), x0, a0);
        a1 = fmaf(__uint_as_float(r1.y), x1, a1);
        a2 = fmaf(__uint_as_float(r2.y), x2, a2);
        a3 = fmaf(__uint_as_float(r3.y), x3, a3);
        a4 = fmaf(__uint_as_float(r4.y), x4, a4);
        a5 = fmaf(__uint_as_float(r5.y), x5, a5);
        a6 = fmaf(__uint_as_float(r6.y), x6, a6);
        a7 = fmaf(__uint_as_float(r7.y), x7, a7);
    }
    for (; k < cnt; ++k) {
        uint2 r = recs[beg + k];
        a0 = fmaf(__uint_as_float(r.y), x[(r.x << 6) + lane], a0);
    }
    agg[(size_t)node * F_XC + lane] =
        ((a0 + a1) + (a2 + a3)) + ((a4 + a5) + (a6 + a7));
}

// ---------------------------------------------------------------------------
// Per-batch global projection: UK[b][j] = b_K[j] + sum_k u[b][k]*W_K[64+k][j]
// ---------------------------------------------------------------------------
__global__ __launch_bounds__(128) void global_proj_kernel(
    const float* __restrict__ u, const float* __restrict__ W_K,
    const float* __restrict__ b_K, const float* __restrict__ W_Q,
    const float* __restrict__ b_Q, float* __restrict__ UK,
    float* __restrict__ UQ)
{
    __shared__ float s_u[F_UC];
    int b = blockIdx.x;
    int j = threadIdx.x;
    s_u[j] = u[(size_t)b * F_UC + j];
    __syncthreads();
    float accK = b_K[j];
    float accQ = b_Q[j];
    #pragma unroll 8
    for (int k = 0; k < F_UC; ++k) {
        float uv = s_u[k];
        accK = fmaf(uv, W_K[(size_t)(F_XC + k) * F_OUTC + j], accK);
        accQ = fmaf(uv, W_Q[(size_t)(F_XC + k) * F_OUTC + j], accQ);
    }
    UK[(size_t)b * F_OUTC + j] = accK;
    UQ[(size_t)b * F_OUTC + j] = accQ;
}

// ---------------------------------------------------------------------------
// Output GEMM: 4 chunks of 32 nodes per block (weight regs amortized 4x).
// 256 threads = 2 nodes x 128 feats in parallel, 16 sequential q-steps.
// ---------------------------------------------------------------------------
__global__ __launch_bounds__(256) void out_csr(
    const float* __restrict__ agg, const int* __restrict__ batch,
    const float* __restrict__ W_K, const float* __restrict__ W_Q,
    const float* __restrict__ UK, const float* __restrict__ UQ,
    float* __restrict__ K_out, float* __restrict__ Q_out, int N)
{
    const int j = threadIdx.x & 127;
    const int half = threadIdx.x >> 7;

    float wk[F_XC], wq[F_XC];
    #pragma unroll
    for (int k = 0; k < F_XC; ++k) {
        wk[k] = W_K[(size_t)k * F_OUTC + j];
        wq[k] = W_Q[(size_t)k * F_OUTC + j];
    }

    __shared__ float s_agg[32][F_XC];   // 8 KB

    #pragma unroll
    for (int c = 0; c < 4; ++c) {
        const int base = blockIdx.x * 128 + c * 32;
        if (base >= N) break;
        __syncthreads();   // protect s_agg from previous chunk's readers
        {   // stage 32 rows (2048 floats) as 512 float4: 2 per thread
            const float4* A4 = (const float4*)(agg + (size_t)base * F_XC);
            float4* S4 = (float4*)s_agg;
            int lim = (N - base) * (F_XC / 4);      // ragged-tail guard
            if (lim > 512) lim = 512;
            int i0 = threadIdx.x, i1 = threadIdx.x + 256;
            if (i0 < lim) S4[i0] = A4[i0];
            if (i1 < lim) S4[i1] = A4[i1];
        }
        __syncthreads();

        #pragma unroll
        for (int q = 0; q < 16; ++q) {
            int n = base + q * 2 + half;
            if (n < N) {
                float accK = 0.f, accQ = 0.f;
                const float4* a4p = (const float4*)s_agg[q * 2 + half];
                #pragma unroll
                for (int k4 = 0; k4 < F_XC / 4; ++k4) {
                    float4 a4 = a4p[k4];
                    accK = fmaf(a4.x, wk[k4 * 4 + 0], accK);
                    accQ = fmaf(a4.x, wq[k4 * 4 + 0], accQ);
                    accK = fmaf(a4.y, wk[k4 * 4 + 1], accK);
                    accQ = fmaf(a4.y, wq[k4 * 4 + 1], accQ);
                    accK = fmaf(a4.z, wk[k4 * 4 + 2], accK);
                    accQ = fmaf(a4.z, wq[k4 * 4 + 2], accQ);
                    accK = fmaf(a4.w, wk[k4 * 4 + 3], accK);
                    accQ = fmaf(a4.w, wq[k4 * 4 + 3], accQ);
                }
                const int bb = batch[n];
                K_out[(size_t)n * F_OUTC + j] = accK + UK[(size_t)bb * F_OUTC + j];
                Q_out[(size_t)n * F_OUTC + j] = accQ + UQ[(size_t)bb * F_OUTC + j];
            }
        }
    }
}

// ---------------------------------------------------------------------------
// Fallback path (fp32 device-atomic scatter), only if ws is too small.
// ---------------------------------------------------------------------------
__global__ __launch_bounds__(256) void scatter_kernel(
    const int* __restrict__ src, const int* __restrict__ dst,
    const float* __restrict__ attr, const float* __restrict__ x,
    float* __restrict__ agg, int E)
{
    int e = blockIdx.x * 4 + (threadIdx.x >> 6);
    int f = threadIdx.x & 63;
    if (e >= E) return;
    atomicAdd(&agg[(size_t)dst[e] * F_XC + f],
              attr[e] * x[(size_t)src[e] * F_XC + f]);
}

// ---------------------------------------------------------------------------
// Launch
// ---------------------------------------------------------------------------
extern "C" void kernel_launch(void* const* d_in, const int* in_sizes, int n_in,
                              void* d_out, int out_size, void* d_ws, size_t ws_size,
                              hipStream_t stream) {
    const float* x         = (const float*)d_in[0];
    const int*   edge_idx  = (const int*)  d_in[1];
    const float* edge_attr = (const float*)d_in[2];
    const float* u         = (const float*)d_in[3];
    const int*   batch     = (const int*)  d_in[4];
    const float* W_K       = (const float*)d_in[5];
    const float* b_K       = (const float*)d_in[6];
    const float* W_Q       = (const float*)d_in[7];
    const float* b_Q       = (const float*)d_in[8];

    const int N = in_sizes[0] / F_XC;       // 100000
    const int E = in_sizes[1] / 2;          // 3200000

    const int* src = edge_idx;
    const int* dst = edge_idx + E;

    float* K_out = (float*)d_out;
    float* Q_out = K_out + (size_t)N * F_OUTC;

    const int NB1024 = (N + 1023) / 1024;    // scan blocks (98)
    const int BSZ    = (N + NBUCK - 1) / NBUCK;  // 782 nodes per coarse bucket

    // CSR workspace: recs [E u2] | agg∪recsA [max(N*64*4, E*8)] | hist [N] |
    //                cursors [N] | partial [NB1024] | gcurA [NBUCK] | UK | UQ
    size_t aggA_bytes = (size_t)N * F_XC * sizeof(float);
    size_t recsA_bytes = (size_t)E * sizeof(uint2);
    size_t unionb = aggA_bytes > recsA_bytes ? aggA_bytes : recsA_bytes;
    size_t need = (size_t)E * sizeof(uint2)
                + unionb
                + 2 * (size_t)N * sizeof(int)
                + (size_t)NB1024 * sizeof(int)
                + (size_t)NBUCK * sizeof(int)
                + 2 * (size_t)B_GLOB * F_OUTC * sizeof(float);

    if (ws_size >= need) {
        uint2* recs    = (uint2*)d_ws;
        char*  unionp  = (char*)(recs + (size_t)E);
        uint2* recsA   = (uint2*)unionp;            // alias: pass A/B scratch
        float* agg     = (float*)unionp;            // alias: live after partB
        int*   hist    = (int*)(unionp + unionb);
        int*   cursors = hist + N;
        int*   partial = cursors + N;
        int*   gcurA   = partial + NB1024;
        float* UK      = (float*)(gcurA + NBUCK);
        float* UQ      = UK + (size_t)B_GLOB * F_OUTC;

        hipMemsetAsync(hist, 0, (size_t)N * sizeof(int), stream);

        hist_kernel<<<(E + 255) / 256, 256, 0, stream>>>(dst, hist, E);
        scan_block_sums<<<NB1024, 1024, 0, stream>>>(hist, partial, N);
        scan_partials<<<1, 128, 0, stream>>>(partial, NB1024);
        scan_final<<<NB1024, 1024, 0, stream>>>(hist, partial, cursors, N);
        initA_kernel<<<1, 128, 0, stream>>>(cursors, gcurA, N, BSZ, E);
        partA_kernel<<<(E + 4095) / 4096, 256, 0, stream>>>(src, dst, edge_attr,
                                                            gcurA, recsA, E, BSZ);
        partB_kernel<<<NBUCK, 1024, 0, stream>>>(recsA, cursors, recs, N, E, BSZ);
        csr_accum<<<(N + 3) / 4, 256, 0, stream>>>(recs, cursors, hist, x, agg, N);
        global_proj_kernel<<<B_GLOB, 128, 0, stream>>>(u, W_K, b_K, W_Q, b_Q, UK, UQ);
        out_csr<<<(N + 127) / 128, 256, 0, stream>>>(agg, batch, W_K, W_Q, UK, UQ,
                                                     K_out, Q_out, N);
    } else {
        float* agg = (float*)d_ws;
        float* UK  = agg + (size_t)N * F_XC;
        float* UQ  = UK + (size_t)B_GLOB * F_OUTC;
        hipMemsetAsync(agg, 0, (size_t)N * F_XC * sizeof(float), stream);
        scatter_kernel<<<(E + 3) / 4, 256, 0, stream>>>(src, dst, edge_attr, x, agg, E);
        global_proj_kernel<<<B_GLOB, 128, 0, stream>>>(u, W_K, b_K, W_Q, b_Q, UK, UQ);
        out_csr<<<(N + 127) / 128, 256, 0, stream>>>(agg, batch, W_K, W_Q, UK, UQ,
                                                     K_out, Q_out, N);
    }
}

// Round 8
// 516.924 us; speedup vs baseline: 3.1619x; 1.1721x over previous
//
#include <hip/hip_runtime.h>

// Problem constants (from reference)
#define F_XC 64
#define F_UC 128
#define F_OUTC 128
#define B_GLOB 512
#define NBUCK 128          // coarse dst-range buckets (pass A/B)

typedef __attribute__((ext_vector_type(8))) short short8;
typedef __attribute__((ext_vector_type(4))) float f32x4;

// fp32 -> bf16 bits, round-to-nearest-even
static __device__ __forceinline__ short f2bf(float f) {
    unsigned u = __float_as_uint(f);
    unsigned r = (u + 0x7FFFu + ((u >> 16) & 1u)) >> 16;
    return (short)r;
}

// ---------------------------------------------------------------------------
// Pass 1: histogram of dest nodes. Small-payload atomics (400 KB counters).
// ---------------------------------------------------------------------------
__global__ __launch_bounds__(256) void hist_kernel(
    const int* __restrict__ dst, int* __restrict__ hist, int E)
{
    int e = blockIdx.x * 256 + threadIdx.x;
    if (e < E) atomicAdd(&hist[dst[e]], 1);
}

// ---------------------------------------------------------------------------
// Pass 2: exclusive scan of hist -> cursors (3 tiny kernels).
// cursors[] is NEVER mutated afterwards (pass B uses LDS copies).
// ---------------------------------------------------------------------------
__global__ __launch_bounds__(1024) void scan_block_sums(
    const int* __restrict__ hist, int* __restrict__ partial, int N)
{
    __shared__ int red[1024];
    int i = blockIdx.x * 1024 + threadIdx.x;
    red[threadIdx.x] = (i < N) ? hist[i] : 0;
    __syncthreads();
    for (int s = 512; s > 0; s >>= 1) {
        if (threadIdx.x < s) red[threadIdx.x] += red[threadIdx.x + s];
        __syncthreads();
    }
    if (threadIdx.x == 0) partial[blockIdx.x] = red[0];
}

__global__ __launch_bounds__(128) void scan_partials(int* __restrict__ partial, int nb)
{
    __shared__ int s[128];
    int t = threadIdx.x;
    int v = (t < nb) ? partial[t] : 0;
    s[t] = v;
    __syncthreads();
    for (int off = 1; off < 128; off <<= 1) {
        int a = (t >= off) ? s[t - off] : 0;
        __syncthreads();
        s[t] += a;
        __syncthreads();
    }
    if (t < nb) partial[t] = s[t] - v;   // exclusive
}

__global__ __launch_bounds__(1024) void scan_final(
    const int* __restrict__ hist, const int* __restrict__ partial,
    int* __restrict__ cursors, int N)
{
    __shared__ int s[1024];
    int t = threadIdx.x, i = blockIdx.x * 1024 + t;
    int v = (i < N) ? hist[i] : 0;
    s[t] = v;
    __syncthreads();
    for (int off = 1; off < 1024; off <<= 1) {
        int a = (t >= off) ? s[t - off] : 0;
        __syncthreads();
        s[t] += a;
        __syncthreads();
    }
    if (i < N) cursors[i] = s[t] - v + partial[blockIdx.x];   // exclusive scan
}

// ---------------------------------------------------------------------------
// Init pass-A write cursors: one per coarse bucket.
// ---------------------------------------------------------------------------
__global__ __launch_bounds__(128) void initA_kernel(
    const int* __restrict__ cursors, int* __restrict__ gcurA, int N, int BSZ, int E)
{
    int b = threadIdx.x;
    if (b < NBUCK) {
        long long idx = (long long)b * BSZ;
        gcurA[b] = (idx < N) ? cursors[idx] : E;
    }
}

// ---------------------------------------------------------------------------
// Pass A: coarse partition into NBUCK dst-range buckets.
// ---------------------------------------------------------------------------
__global__ __launch_bounds__(256) void partA_kernel(
    const int* __restrict__ src, const int* __restrict__ dst,
    const float* __restrict__ attr, int* __restrict__ gcurA,
    uint2* __restrict__ recsA, int E, int BSZ)
{
    __shared__ int lhist[NBUCK];
    __shared__ int lbase[NBUCK];
    if (threadIdx.x < NBUCK) lhist[threadIdx.x] = 0;
    __syncthreads();

    const int cbase = blockIdx.x * 4096;
    unsigned pk[16];
    float    av[16];
    unsigned meta[16];

    #pragma unroll
    for (int i = 0; i < 16; ++i) {
        int e = cbase + i * 256 + threadIdx.x;
        if (e < E) {
            int d = dst[e];
            int b = d / BSZ;
            int r = atomicAdd(&lhist[b], 1);            // LDS atomic: rank
            pk[i]   = (unsigned)src[e] | ((unsigned)(d - b * BSZ) << 17);
            av[i]   = attr[e];
            meta[i] = (unsigned)b | ((unsigned)r << 8);
        } else {
            meta[i] = 0xFFFFFFFFu;
        }
    }
    __syncthreads();
    if (threadIdx.x < NBUCK)
        lbase[threadIdx.x] = atomicAdd(&gcurA[threadIdx.x], lhist[threadIdx.x]);
    __syncthreads();

    #pragma unroll
    for (int i = 0; i < 16; ++i) {
        if (meta[i] != 0xFFFFFFFFu) {
            int b = meta[i] & 0xFF;
            int r = (int)(meta[i] >> 8);
            recsA[lbase[b] + r] = make_uint2(pk[i], __float_as_uint(av[i]));
        }
    }
}

// ---------------------------------------------------------------------------
// Pass B: fine CSR placement within each bucket (LDS cursors, local window).
// ---------------------------------------------------------------------------
__global__ __launch_bounds__(1024) void partB_kernel(
    const uint2* __restrict__ recsA, const int* __restrict__ cursors,
    uint2* __restrict__ recs, int N, int E, int BSZ)
{
    __shared__ int Lcur[1024];            // BSZ <= 1024 for this problem size
    const int b  = blockIdx.x;
    const int lo = b * BSZ;
    const int hi = (lo + BSZ < N) ? lo + BSZ : N;
    const int bsz = hi - lo;
    if ((int)threadIdx.x < bsz) Lcur[threadIdx.x] = cursors[lo + threadIdx.x];
    __syncthreads();

    const int rbeg = cursors[lo];
    const int rend = (hi < N) ? cursors[hi] : E;
    for (int r = rbeg + threadIdx.x; r < rend; r += 1024) {
        uint2 v = recsA[r];
        int dl  = (int)(v.x >> 17);
        int pos = atomicAdd(&Lcur[dl], 1);            // LDS atomic
        recs[pos] = make_uint2(v.x & 0x1FFFFu, v.y);
    }
}

// ---------------------------------------------------------------------------
// Pass 4: CSR accumulate. One wave per dest node; lane f owns feature f.
// 8 independent FMA chains / 16 loads in flight per wave.
// ---------------------------------------------------------------------------
__global__ __launch_bounds__(256) void csr_accum(
    const uint2* __restrict__ recs, const int* __restrict__ cursors,
    const int* __restrict__ hist, const float* __restrict__ x,
    float* __restrict__ agg, int N)
{
    int node = blockIdx.x * 4 + (threadIdx.x >> 6);
    int lane = threadIdx.x & 63;
    if (node >= N) return;
    int cnt = hist[node];
    int beg = cursors[node];

    float a0 = 0.f, a1 = 0.f, a2 = 0.f, a3 = 0.f;
    float a4 = 0.f, a5 = 0.f, a6 = 0.f, a7 = 0.f;
    int k = 0;
    for (; k + 8 <= cnt; k += 8) {
        uint2 r0 = recs[beg + k + 0];
        uint2 r1 = recs[beg + k + 1];
        uint2 r2 = recs[beg + k + 2];
        uint2 r3 = recs[beg + k + 3];
        uint2 r4 = recs[beg + k + 4];
        uint2 r5 = recs[beg + k + 5];
        uint2 r6 = recs[beg + k + 6];
        uint2 r7 = recs[beg + k + 7];
        float x0 = x[(r0.x << 6) + lane];
        float x1 = x[(r1.x << 6) + lane];
        float x2 = x[(r2.x << 6) + lane];
        float x3 = x[(r3.x << 6) + lane];
        float x4 = x[(r4.x << 6) + lane];
        float x5 = x[(r5.x << 6) + lane];
        float x6 = x[(r6.x << 6) + lane];
        float x7 = x[(r7.x << 6) + lane];
        a0 = fmaf(__uint_as_float(r0.y), x0, a0);
        a1 = fmaf(__uint_as_float(r1.y), x1, a1);
        a2 = fmaf(__uint_as_float(r2.y), x2, a2);
        a3 = fmaf(__uint_as_float(r3.y), x3, a3);
        a4 = fmaf(__uint_as_float(r4.y), x4, a4);
        a5 = fmaf(__uint_as_float(r5.y), x5, a5);
        a6 = fmaf(__uint_as_float(r6.y), x6, a6);
        a7 = fmaf(__uint_as_float(r7.y), x7, a7);
    }
    for (; k < cnt; ++k) {
        uint2 r = recs[beg + k];
        a0 = fmaf(__uint_as_float(r.y), x[(r.x << 6) + lane], a0);
    }
    agg[(size_t)node * F_XC + lane] =
        ((a0 + a1) + (a2 + a3)) + ((a4 + a5) + (a6 + a7));
}

// ---------------------------------------------------------------------------
// Per-batch global projection: UK[b][j] = b_K[j] + sum_k u[b][k]*W_K[64+k][j]
// ---------------------------------------------------------------------------
__global__ __launch_bounds__(128) void global_proj_kernel(
    const float* __restrict__ u, const float* __restrict__ W_K,
    const float* __restrict__ b_K, const float* __restrict__ W_Q,
    const float* __restrict__ b_Q, float* __restrict__ UK,
    float* __restrict__ UQ)
{
    __shared__ float s_u[F_UC];
    int b = blockIdx.x;
    int j = threadIdx.x;
    s_u[j] = u[(size_t)b * F_UC + j];
    __syncthreads();
    float accK = b_K[j];
    float accQ = b_Q[j];
    #pragma unroll 8
    for (int k = 0; k < F_UC; ++k) {
        float uv = s_u[k];
        accK = fmaf(uv, W_K[(size_t)(F_XC + k) * F_OUTC + j], accK);
        accQ = fmaf(uv, W_Q[(size_t)(F_XC + k) * F_OUTC + j], accQ);
    }
    UK[(size_t)b * F_OUTC + j] = accK;
    UQ[(size_t)b * F_OUTC + j] = accQ;
}

// ---------------------------------------------------------------------------
// Pack W_K|W_Q (rows 0..63, the agg part) into MFMA B-fragment layout, bf16.
// Wp[ct][kt][lane][i]: ct 0..15 (ct<8 -> W_K cols, else W_Q), kt 0..1,
// B[k][col] with col = ct_base + (lane&15), k = kt*32 + (lane>>4)*8 + i.
// ---------------------------------------------------------------------------
__global__ __launch_bounds__(256) void pack_w_kernel(
    const float* __restrict__ W_K, const float* __restrict__ W_Q,
    short* __restrict__ Wp)
{
    int idx = blockIdx.x * 256 + threadIdx.x;   // 0..2047 over 8 blocks
    int lane = idx & 63;
    int kt   = (idx >> 6) & 1;
    int ct   = idx >> 7;
    const float* W = (ct < 8) ? W_K : W_Q;
    int col = (ct & 7) * 16 + (lane & 15);
    int kb  = kt * 32 + (lane >> 4) * 8;
    short* o = Wp + (size_t)idx * 8;
    #pragma unroll
    for (int i = 0; i < 8; ++i)
        o[i] = f2bf(W[(size_t)(kb + i) * F_OUTC + col]);
}

// ---------------------------------------------------------------------------
// Output GEMM via bf16 MFMA (16x16x32), A = agg split hi/lo bf16, B = Wp.
// Block = 4 waves; wave w owns 64 output cols: w0,w1 -> K[0:64),K[64:128);
// w2,w3 -> Q. Each block processes 4 chunks of 16 rows. No LDS, no barriers.
// Epilogue adds UK/UQ[batch[row]] (bias folded there) in fp32.
// A-frag: lane l holds A[m0+(l&15)][kt*32+(l>>4)*8 + i]; C/D: row=
// m0+(l>>4)*4+reg, col=(l&15) [guide §3, m89-verified].
// ---------------------------------------------------------------------------
__global__ __launch_bounds__(256) void out_mfma(
    const float* __restrict__ agg, const int* __restrict__ batch,
    const short* __restrict__ Wp, const float* __restrict__ UK,
    const float* __restrict__ UQ, float* __restrict__ K_out,
    float* __restrict__ Q_out, int N)
{
    const int w    = threadIdx.x >> 6;
    const int lane = threadIdx.x & 63;
    const int lmod = lane & 15;
    const int ldiv = lane >> 4;

    // B fragments: 4 col-tiles x 2 k-tiles, loaded once per block (L2-hot)
    short8 bfrag[4][2];
    #pragma unroll
    for (int c = 0; c < 4; ++c)
        #pragma unroll
        for (int kt = 0; kt < 2; ++kt)
            bfrag[c][kt] =
                *(const short8*)&Wp[(size_t)(((w * 4 + c) * 2 + kt) * 64 + lane) * 8];

    const float* Uv  = (w < 2) ? UK : UQ;
    float*       out = (w < 2) ? K_out : Q_out;
    const int colb0 = (w & 1) * 64;

    #pragma unroll
    for (int ch = 0; ch < 4; ++ch) {
        const int m0 = (blockIdx.x * 4 + ch) * 16;
        if (m0 >= N) break;

        // A fragments: 2 k-tiles, hi/lo bf16 split (fp32-accurate A)
        short8 ahi[2], alo[2];
        #pragma unroll
        for (int kt = 0; kt < 2; ++kt) {
            const float* ap = agg + (size_t)(m0 + lmod) * F_XC + kt * 32 + ldiv * 8;
            #pragma unroll
            for (int i = 0; i < 8; ++i) {
                float f  = ap[i];
                short hb = f2bf(f);
                float hf = __uint_as_float(((unsigned)(unsigned short)hb) << 16);
                ahi[kt][i] = hb;
                alo[kt][i] = f2bf(f - hf);
            }
        }

        f32x4 acc[4] = {{0.f, 0.f, 0.f, 0.f}, {0.f, 0.f, 0.f, 0.f},
                        {0.f, 0.f, 0.f, 0.f}, {0.f, 0.f, 0.f, 0.f}};
        #pragma unroll
        for (int c = 0; c < 4; ++c) {
            #pragma unroll
            for (int kt = 0; kt < 2; ++kt) {
                acc[c] = __builtin_amdgcn_mfma_f32_16x16x32_bf16(
                    ahi[kt], bfrag[c][kt], acc[c], 0, 0, 0);
                acc[c] = __builtin_amdgcn_mfma_f32_16x16x32_bf16(
                    alo[kt], bfrag[c][kt], acc[c], 0, 0, 0);
            }
        }

        int bb[4];
        #pragma unroll
        for (int r = 0; r < 4; ++r) bb[r] = batch[m0 + ldiv * 4 + r];

        #pragma unroll
        for (int c = 0; c < 4; ++c) {
            const int col = colb0 + c * 16 + lmod;
            #pragma unroll
            for (int r = 0; r < 4; ++r) {
                const int row = m0 + ldiv * 4 + r;
                out[(size_t)row * F_OUTC + col] =
                    acc[c][r] + Uv[(size_t)bb[r] * F_OUTC + col];
            }
        }
    }
}

// ---------------------------------------------------------------------------
// Fallback path kernels (ws too small): fp32 atomic scatter + VALU out GEMM.
// ---------------------------------------------------------------------------
__global__ __launch_bounds__(256) void scatter_kernel(
    const int* __restrict__ src, const int* __restrict__ dst,
    const float* __restrict__ attr, const float* __restrict__ x,
    float* __restrict__ agg, int E)
{
    int e = blockIdx.x * 4 + (threadIdx.x >> 6);
    int f = threadIdx.x & 63;
    if (e >= E) return;
    atomicAdd(&agg[(size_t)dst[e] * F_XC + f],
              attr[e] * x[(size_t)src[e] * F_XC + f]);
}

__global__ __launch_bounds__(256) void out_csr(
    const float* __restrict__ agg, const int* __restrict__ batch,
    const float* __restrict__ W_K, const float* __restrict__ W_Q,
    const float* __restrict__ UK, const float* __restrict__ UQ,
    float* __restrict__ K_out, float* __restrict__ Q_out, int N)
{
    const int j = threadIdx.x & 127;
    const int half = threadIdx.x >> 7;
    float wk[F_XC], wq[F_XC];
    #pragma unroll
    for (int k = 0; k < F_XC; ++k) {
        wk[k] = W_K[(size_t)k * F_OUTC + j];
        wq[k] = W_Q[(size_t)k * F_OUTC + j];
    }
    __shared__ float s_agg[32][F_XC];
    #pragma unroll
    for (int c = 0; c < 4; ++c) {
        const int base = blockIdx.x * 128 + c * 32;
        if (base >= N) break;
        __syncthreads();
        {
            const float4* A4 = (const float4*)(agg + (size_t)base * F_XC);
            float4* S4 = (float4*)s_agg;
            int lim = (N - base) * (F_XC / 4);
            if (lim > 512) lim = 512;
            int i0 = threadIdx.x, i1 = threadIdx.x + 256;
            if (i0 < lim) S4[i0] = A4[i0];
            if (i1 < lim) S4[i1] = A4[i1];
        }
        __syncthreads();
        #pragma unroll
        for (int q = 0; q < 16; ++q) {
            int n = base + q * 2 + half;
            if (n < N) {
                float accK = 0.f, accQ = 0.f;
                const float4* a4p = (const float4*)s_agg[q * 2 + half];
                #pragma unroll
                for (int k4 = 0; k4 < F_XC / 4; ++k4) {
                    float4 a4 = a4p[k4];
                    accK = fmaf(a4.x, wk[k4 * 4 + 0], accK);
                    accQ = fmaf(a4.x, wq[k4 * 4 + 0], accQ);
                    accK = fmaf(a4.y, wk[k4 * 4 + 1], accK);
                    accQ = fmaf(a4.y, wq[k4 * 4 + 1], accQ);
                    accK = fmaf(a4.z, wk[k4 * 4 + 2], accK);
                    accQ = fmaf(a4.z, wq[k4 * 4 + 2], accQ);
                    accK = fmaf(a4.w, wk[k4 * 4 + 3], accK);
                    accQ = fmaf(a4.w, wq[k4 * 4 + 3], accQ);
                }
                const int bb = batch[n];
                K_out[(size_t)n * F_OUTC + j] = accK + UK[(size_t)bb * F_OUTC + j];
                Q_out[(size_t)n * F_OUTC + j] = accQ + UQ[(size_t)bb * F_OUTC + j];
            }
        }
    }
}

// ---------------------------------------------------------------------------
// Launch
// ---------------------------------------------------------------------------
extern "C" void kernel_launch(void* const* d_in, const int* in_sizes, int n_in,
                              void* d_out, int out_size, void* d_ws, size_t ws_size,
                              hipStream_t stream) {
    const float* x         = (const float*)d_in[0];
    const int*   edge_idx  = (const int*)  d_in[1];
    const float* edge_attr = (const float*)d_in[2];
    const float* u         = (const float*)d_in[3];
    const int*   batch     = (const int*)  d_in[4];
    const float* W_K       = (const float*)d_in[5];
    const float* b_K       = (const float*)d_in[6];
    const float* W_Q       = (const float*)d_in[7];
    const float* b_Q       = (const float*)d_in[8];

    const int N = in_sizes[0] / F_XC;       // 100000
    const int E = in_sizes[1] / 2;          // 3200000

    const int* src = edge_idx;
    const int* dst = edge_idx + E;

    float* K_out = (float*)d_out;
    float* Q_out = K_out + (size_t)N * F_OUTC;

    const int NB1024 = (N + 1023) / 1024;        // scan blocks (98)
    const int BSZ    = (N + NBUCK - 1) / NBUCK;  // 782 nodes per coarse bucket

    // CSR workspace: recs [E u2] | agg∪recsA [max(N*64*4, E*8)] | hist [N] |
    //                cursors [N] | partial | gcurA | UK | UQ | Wp [16K shorts]
    size_t aggA_bytes  = (size_t)N * F_XC * sizeof(float);
    size_t recsA_bytes = (size_t)E * sizeof(uint2);
    size_t unionb = aggA_bytes > recsA_bytes ? aggA_bytes : recsA_bytes;
    size_t need = (size_t)E * sizeof(uint2)
                + unionb
                + 2 * (size_t)N * sizeof(int)
                + (size_t)NB1024 * sizeof(int)
                + (size_t)NBUCK * sizeof(int)
                + 2 * (size_t)B_GLOB * F_OUTC * sizeof(float)
                + (size_t)16384 * sizeof(short);

    if (ws_size >= need) {
        uint2* recs    = (uint2*)d_ws;
        char*  unionp  = (char*)(recs + (size_t)E);
        uint2* recsA   = (uint2*)unionp;            // alias: pass A/B scratch
        float* agg     = (float*)unionp;            // alias: live after partB
        int*   hist    = (int*)(unionp + unionb);
        int*   cursors = hist + N;
        int*   partial = cursors + N;
        int*   gcurA   = partial + NB1024;
        float* UK      = (float*)(gcurA + NBUCK);
        float* UQ      = UK + (size_t)B_GLOB * F_OUTC;
        short* Wp      = (short*)(UQ + (size_t)B_GLOB * F_OUTC);

        hipMemsetAsync(hist, 0, (size_t)N * sizeof(int), stream);

        hist_kernel<<<(E + 255) / 256, 256, 0, stream>>>(dst, hist, E);
        scan_block_sums<<<NB1024, 1024, 0, stream>>>(hist, partial, N);
        scan_partials<<<1, 128, 0, stream>>>(partial, NB1024);
        scan_final<<<NB1024, 1024, 0, stream>>>(hist, partial, cursors, N);
        initA_kernel<<<1, 128, 0, stream>>>(cursors, gcurA, N, BSZ, E);
        partA_kernel<<<(E + 4095) / 4096, 256, 0, stream>>>(src, dst, edge_attr,
                                                            gcurA, recsA, E, BSZ);
        partB_kernel<<<NBUCK, 1024, 0, stream>>>(recsA, cursors, recs, N, E, BSZ);
        csr_accum<<<(N + 3) / 4, 256, 0, stream>>>(recs, cursors, hist, x, agg, N);
        global_proj_kernel<<<B_GLOB, 128, 0, stream>>>(u, W_K, b_K, W_Q, b_Q, UK, UQ);
        pack_w_kernel<<<8, 256, 0, stream>>>(W_K, W_Q, Wp);

        const int nch  = (N + 15) / 16;
        const int nblk = (nch + 3) / 4;
        out_mfma<<<nblk, 256, 0, stream>>>(agg, batch, Wp, UK, UQ,
                                           K_out, Q_out, N);
    } else {
        float* agg = (float*)d_ws;
        float* UK  = agg + (size_t)N * F_XC;
        float* UQ  = UK + (size_t)B_GLOB * F_OUTC;
        hipMemsetAsync(agg, 0, (size_t)N * F_XC * sizeof(float), stream);
        scatter_kernel<<<(E + 3) / 4, 256, 0, stream>>>(src, dst, edge_attr, x, agg, E);
        global_proj_kernel<<<B_GLOB, 128, 0, stream>>>(u, W_K, b_K, W_Q, b_Q, UK, UQ);
        out_csr<<<(N + 127) / 128, 256, 0, stream>>>(agg, batch, W_K, W_Q, UK, UQ,
                                                     K_out, Q_out, N);
    }
}

// Round 9
// 409.108 us; speedup vs baseline: 3.9952x; 1.2635x over previous
//
#include <hip/hip_runtime.h>

// Problem constants (from reference)
#define F_XC 64
#define F_UC 128
#define F_OUTC 128
#define B_GLOB 512
#define NBUCK 128          // coarse dst-range buckets (pass A/B)

typedef __attribute__((ext_vector_type(8))) short short8;
typedef __attribute__((ext_vector_type(4))) float f32x4;

// fp32 -> bf16 bits, round-to-nearest-even
static __device__ __forceinline__ short f2bf(float f) {
    unsigned u = __float_as_uint(f);
    unsigned r = (u + 0x7FFFu + ((u >> 16) & 1u)) >> 16;
    return (short)r;
}

// ---------------------------------------------------------------------------
// Pass 1: coarse bucket histogram. LDS-privatized (128 counters/block), then
// 128 global atomics per block -> 100k small atomics total (vs 3.2M full-res
// hist whose 32B/op write-through cost 129 us in round 8).
// ---------------------------------------------------------------------------
__global__ __launch_bounds__(256) void bucket_hist(
    const int* __restrict__ dst, int* __restrict__ bucketCnt, int E, int BSZ)
{
    __shared__ int lh[NBUCK];
    if (threadIdx.x < NBUCK) lh[threadIdx.x] = 0;
    __syncthreads();
    const int cbase = blockIdx.x * 4096;
    #pragma unroll
    for (int i = 0; i < 16; ++i) {
        int e = cbase + i * 256 + threadIdx.x;
        if (e < E) atomicAdd(&lh[dst[e] / BSZ], 1);
    }
    __syncthreads();
    if (threadIdx.x < NBUCK && lh[threadIdx.x] != 0)
        atomicAdd(&bucketCnt[threadIdx.x], lh[threadIdx.x]);
}

// ---------------------------------------------------------------------------
// Pass 2: scan 128 bucket counts -> bucketOff[0..NBUCK], init gcurA.
// ---------------------------------------------------------------------------
__global__ __launch_bounds__(128) void bucket_scan(
    const int* __restrict__ bucketCnt, int* __restrict__ bucketOff,
    int* __restrict__ gcurA)
{
    __shared__ int s[NBUCK];
    int t = threadIdx.x;
    int v = bucketCnt[t];
    s[t] = v;
    __syncthreads();
    for (int off = 1; off < NBUCK; off <<= 1) {
        int a = (t >= off) ? s[t - off] : 0;
        __syncthreads();
        s[t] += a;
        __syncthreads();
    }
    int excl = s[t] - v;
    bucketOff[t] = excl;
    gcurA[t] = excl;
    if (t == NBUCK - 1) bucketOff[NBUCK] = s[t];
}

// ---------------------------------------------------------------------------
// Pass A: coarse partition into NBUCK dst-range buckets.
// Per block: LDS histogram over 4096 edges -> 128 global atomics reserve
// contiguous runs -> grouped writes. Record packs src(17b) | dlocal<<17.
// ---------------------------------------------------------------------------
__global__ __launch_bounds__(256) void partA_kernel(
    const int* __restrict__ src, const int* __restrict__ dst,
    const float* __restrict__ attr, int* __restrict__ gcurA,
    uint2* __restrict__ recsA, int E, int BSZ)
{
    __shared__ int lhist[NBUCK];
    __shared__ int lbase[NBUCK];
    if (threadIdx.x < NBUCK) lhist[threadIdx.x] = 0;
    __syncthreads();

    const int cbase = blockIdx.x * 4096;
    unsigned pk[16];
    float    av[16];
    unsigned meta[16];

    #pragma unroll
    for (int i = 0; i < 16; ++i) {
        int e = cbase + i * 256 + threadIdx.x;
        if (e < E) {
            int d = dst[e];
            int b = d / BSZ;
            int r = atomicAdd(&lhist[b], 1);            // LDS atomic: rank
            pk[i]   = (unsigned)src[e] | ((unsigned)(d - b * BSZ) << 17);
            av[i]   = attr[e];
            meta[i] = (unsigned)b | ((unsigned)r << 8);
        } else {
            meta[i] = 0xFFFFFFFFu;
        }
    }
    __syncthreads();
    if (threadIdx.x < NBUCK)
        lbase[threadIdx.x] = atomicAdd(&gcurA[threadIdx.x], lhist[threadIdx.x]);
    __syncthreads();

    #pragma unroll
    for (int i = 0; i < 16; ++i) {
        if (meta[i] != 0xFFFFFFFFu) {
            int b = meta[i] & 0xFF;
            int r = (int)(meta[i] >> 8);
            recsA[lbase[b] + r] = make_uint2(pk[i], __float_as_uint(av[i]));
        }
    }
}

// ---------------------------------------------------------------------------
// Pass B (fused): per bucket -- LDS fine histogram of dlocal from the recsA
// slice (L2-hot), LDS scan -> write hist[] & cursors[] (coalesced, no global
// hist atomics anywhere), then place records into CSR with LDS cursors.
// Write window stays bucket-local (~200-400 KB) -> full-line evictions.
// ---------------------------------------------------------------------------
__global__ __launch_bounds__(1024) void partB_fused(
    const uint2* __restrict__ recsA, const int* __restrict__ bucketOff,
    uint2* __restrict__ recs, int* __restrict__ hist, int* __restrict__ cursors,
    int N, int BSZ)
{
    __shared__ int Lhist[1024];
    __shared__ int Lcur[1024];
    const int t  = threadIdx.x;
    const int b  = blockIdx.x;
    const int lo = b * BSZ;
    const int hi = (lo + BSZ < N) ? lo + BSZ : N;
    const int bsz = hi - lo;

    Lhist[t] = 0;
    __syncthreads();

    const int rbeg = bucketOff[b];
    const int rend = bucketOff[b + 1];

    // pass 1: fine histogram in LDS
    for (int r = rbeg + t; r < rend; r += 1024)
        atomicAdd(&Lhist[recsA[r].x >> 17], 1);
    __syncthreads();

    // LDS Hillis-Steele inclusive scan over 1024 entries
    int v = Lhist[t];
    Lcur[t] = v;
    __syncthreads();
    for (int off = 1; off < 1024; off <<= 1) {
        int a = (t >= off) ? Lcur[t - off] : 0;
        __syncthreads();
        Lcur[t] += a;
        __syncthreads();
    }
    // exclusive + global base; publish hist/cursors for csr_accum
    int start = rbeg + Lcur[t] - v;
    if (t < bsz) {
        hist[lo + t]    = v;
        cursors[lo + t] = start;
    }
    Lcur[t] = start;
    __syncthreads();

    // pass 2: placement (recsA slice re-read is L2-resident)
    for (int r = rbeg + t; r < rend; r += 1024) {
        uint2 rec = recsA[r];
        int dl  = (int)(rec.x >> 17);
        int pos = atomicAdd(&Lcur[dl], 1);            // LDS atomic
        recs[pos] = make_uint2(rec.x & 0x1FFFFu, rec.y);
    }
}

// ---------------------------------------------------------------------------
// Pass 4: CSR accumulate. One wave per dest node; lane f owns feature f.
// 8 independent FMA chains / 16 loads in flight per wave.
// ---------------------------------------------------------------------------
__global__ __launch_bounds__(256) void csr_accum(
    const uint2* __restrict__ recs, const int* __restrict__ cursors,
    const int* __restrict__ hist, const float* __restrict__ x,
    float* __restrict__ agg, int N)
{
    int node = blockIdx.x * 4 + (threadIdx.x >> 6);
    int lane = threadIdx.x & 63;
    if (node >= N) return;
    int cnt = hist[node];
    int beg = cursors[node];

    float a0 = 0.f, a1 = 0.f, a2 = 0.f, a3 = 0.f;
    float a4 = 0.f, a5 = 0.f, a6 = 0.f, a7 = 0.f;
    int k = 0;
    for (; k + 8 <= cnt; k += 8) {
        uint2 r0 = recs[beg + k + 0];
        uint2 r1 = recs[beg + k + 1];
        uint2 r2 = recs[beg + k + 2];
        uint2 r3 = recs[beg + k + 3];
        uint2 r4 = recs[beg + k + 4];
        uint2 r5 = recs[beg + k + 5];
        uint2 r6 = recs[beg + k + 6];
        uint2 r7 = recs[beg + k + 7];
        float x0 = x[(r0.x << 6) + lane];
        float x1 = x[(r1.x << 6) + lane];
        float x2 = x[(r2.x << 6) + lane];
        float x3 = x[(r3.x << 6) + lane];
        float x4 = x[(r4.x << 6) + lane];
        float x5 = x[(r5.x << 6) + lane];
        float x6 = x[(r6.x << 6) + lane];
        float x7 = x[(r7.x << 6) + lane];
        a0 = fmaf(__uint_as_float(r0.y), x0, a0);
        a1 = fmaf(__uint_as_float(r1.y), x1, a1);
        a2 = fmaf(__uint_as_float(r2.y), x2, a2);
        a3 = fmaf(__uint_as_float(r3.y), x3, a3);
        a4 = fmaf(__uint_as_float(r4.y), x4, a4);
        a5 = fmaf(__uint_as_float(r5.y), x5, a5);
        a6 = fmaf(__uint_as_float(r6.y), x6, a6);
        a7 = fmaf(__uint_as_float(r7.y), x7, a7);
    }
    for (; k < cnt; ++k) {
        uint2 r = recs[beg + k];
        a0 = fmaf(__uint_as_float(r.y), x[(r.x << 6) + lane], a0);
    }
    agg[(size_t)node * F_XC + lane] =
        ((a0 + a1) + (a2 + a3)) + ((a4 + a5) + (a6 + a7));
}

// ---------------------------------------------------------------------------
// Per-batch global projection: UK[b][j] = b_K[j] + sum_k u[b][k]*W_K[64+k][j]
// ---------------------------------------------------------------------------
__global__ __launch_bounds__(128) void global_proj_kernel(
    const float* __restrict__ u, const float* __restrict__ W_K,
    const float* __restrict__ b_K, const float* __restrict__ W_Q,
    const float* __restrict__ b_Q, float* __restrict__ UK,
    float* __restrict__ UQ)
{
    __shared__ float s_u[F_UC];
    int b = blockIdx.x;
    int j = threadIdx.x;
    s_u[j] = u[(size_t)b * F_UC + j];
    __syncthreads();
    float accK = b_K[j];
    float accQ = b_Q[j];
    #pragma unroll 8
    for (int k = 0; k < F_UC; ++k) {
        float uv = s_u[k];
        accK = fmaf(uv, W_K[(size_t)(F_XC + k) * F_OUTC + j], accK);
        accQ = fmaf(uv, W_Q[(size_t)(F_XC + k) * F_OUTC + j], accQ);
    }
    UK[(size_t)b * F_OUTC + j] = accK;
    UQ[(size_t)b * F_OUTC + j] = accQ;
}

// ---------------------------------------------------------------------------
// Pack W_K|W_Q (rows 0..63, the agg part) into MFMA B-fragment layout, bf16.
// ---------------------------------------------------------------------------
__global__ __launch_bounds__(256) void pack_w_kernel(
    const float* __restrict__ W_K, const float* __restrict__ W_Q,
    short* __restrict__ Wp)
{
    int idx = blockIdx.x * 256 + threadIdx.x;   // 0..2047 over 8 blocks
    int lane = idx & 63;
    int kt   = (idx >> 6) & 1;
    int ct   = idx >> 7;
    const float* W = (ct < 8) ? W_K : W_Q;
    int col = (ct & 7) * 16 + (lane & 15);
    int kb  = kt * 32 + (lane >> 4) * 8;
    short* o = Wp + (size_t)idx * 8;
    #pragma unroll
    for (int i = 0; i < 8; ++i)
        o[i] = f2bf(W[(size_t)(kb + i) * F_OUTC + col]);
}

// ---------------------------------------------------------------------------
// Output GEMM via bf16 MFMA (16x16x32), A = agg split hi/lo bf16, B = Wp.
// ---------------------------------------------------------------------------
__global__ __launch_bounds__(256) void out_mfma(
    const float* __restrict__ agg, const int* __restrict__ batch,
    const short* __restrict__ Wp, const float* __restrict__ UK,
    const float* __restrict__ UQ, float* __restrict__ K_out,
    float* __restrict__ Q_out, int N)
{
    const int w    = threadIdx.x >> 6;
    const int lane = threadIdx.x & 63;
    const int lmod = lane & 15;
    const int ldiv = lane >> 4;

    // B fragments: 4 col-tiles x 2 k-tiles, loaded once per block (L2-hot)
    short8 bfrag[4][2];
    #pragma unroll
    for (int c = 0; c < 4; ++c)
        #pragma unroll
        for (int kt = 0; kt < 2; ++kt)
            bfrag[c][kt] =
                *(const short8*)&Wp[(size_t)(((w * 4 + c) * 2 + kt) * 64 + lane) * 8];

    const float* Uv  = (w < 2) ? UK : UQ;
    float*       out = (w < 2) ? K_out : Q_out;
    const int colb0 = (w & 1) * 64;

    #pragma unroll
    for (int ch = 0; ch < 4; ++ch) {
        const int m0 = (blockIdx.x * 4 + ch) * 16;
        if (m0 >= N) break;

        // A fragments: 2 k-tiles, hi/lo bf16 split (fp32-accurate A)
        short8 ahi[2], alo[2];
        #pragma unroll
        for (int kt = 0; kt < 2; ++kt) {
            const float* ap = agg + (size_t)(m0 + lmod) * F_XC + kt * 32 + ldiv * 8;
            #pragma unroll
            for (int i = 0; i < 8; ++i) {
                float f  = ap[i];
                short hb = f2bf(f);
                float hf = __uint_as_float(((unsigned)(unsigned short)hb) << 16);
                ahi[kt][i] = hb;
                alo[kt][i] = f2bf(f - hf);
            }
        }

        f32x4 acc[4] = {{0.f, 0.f, 0.f, 0.f}, {0.f, 0.f, 0.f, 0.f},
                        {0.f, 0.f, 0.f, 0.f}, {0.f, 0.f, 0.f, 0.f}};
        #pragma unroll
        for (int c = 0; c < 4; ++c) {
            #pragma unroll
            for (int kt = 0; kt < 2; ++kt) {
                acc[c] = __builtin_amdgcn_mfma_f32_16x16x32_bf16(
                    ahi[kt], bfrag[c][kt], acc[c], 0, 0, 0);
                acc[c] = __builtin_amdgcn_mfma_f32_16x16x32_bf16(
                    alo[kt], bfrag[c][kt], acc[c], 0, 0, 0);
            }
        }

        int bb[4];
        #pragma unroll
        for (int r = 0; r < 4; ++r) bb[r] = batch[m0 + ldiv * 4 + r];

        #pragma unroll
        for (int c = 0; c < 4; ++c) {
            const int col = colb0 + c * 16 + lmod;
            #pragma unroll
            for (int r = 0; r < 4; ++r) {
                const int row = m0 + ldiv * 4 + r;
                out[(size_t)row * F_OUTC + col] =
                    acc[c][r] + Uv[(size_t)bb[r] * F_OUTC + col];
            }
        }
    }
}

// ---------------------------------------------------------------------------
// Fallback path kernels (ws too small): fp32 atomic scatter + VALU out GEMM.
// ---------------------------------------------------------------------------
__global__ __launch_bounds__(256) void scatter_kernel(
    const int* __restrict__ src, const int* __restrict__ dst,
    const float* __restrict__ attr, const float* __restrict__ x,
    float* __restrict__ agg, int E)
{
    int e = blockIdx.x * 4 + (threadIdx.x >> 6);
    int f = threadIdx.x & 63;
    if (e >= E) return;
    atomicAdd(&agg[(size_t)dst[e] * F_XC + f],
              attr[e] * x[(size_t)src[e] * F_XC + f]);
}

__global__ __launch_bounds__(256) void out_csr(
    const float* __restrict__ agg, const int* __restrict__ batch,
    const float* __restrict__ W_K, const float* __restrict__ W_Q,
    const float* __restrict__ UK, const float* __restrict__ UQ,
    float* __restrict__ K_out, float* __restrict__ Q_out, int N)
{
    const int j = threadIdx.x & 127;
    const int half = threadIdx.x >> 7;
    float wk[F_XC], wq[F_XC];
    #pragma unroll
    for (int k = 0; k < F_XC; ++k) {
        wk[k] = W_K[(size_t)k * F_OUTC + j];
        wq[k] = W_Q[(size_t)k * F_OUTC + j];
    }
    __shared__ float s_agg[32][F_XC];
    #pragma unroll
    for (int c = 0; c < 4; ++c) {
        const int base = blockIdx.x * 128 + c * 32;
        if (base >= N) break;
        __syncthreads();
        {
            const float4* A4 = (const float4*)(agg + (size_t)base * F_XC);
            float4* S4 = (float4*)s_agg;
            int lim = (N - base) * (F_XC / 4);
            if (lim > 512) lim = 512;
            int i0 = threadIdx.x, i1 = threadIdx.x + 256;
            if (i0 < lim) S4[i0] = A4[i0];
            if (i1 < lim) S4[i1] = A4[i1];
        }
        __syncthreads();
        #pragma unroll
        for (int q = 0; q < 16; ++q) {
            int n = base + q * 2 + half;
            if (n < N) {
                float accK = 0.f, accQ = 0.f;
                const float4* a4p = (const float4*)s_agg[q * 2 + half];
                #pragma unroll
                for (int k4 = 0; k4 < F_XC / 4; ++k4) {
                    float4 a4 = a4p[k4];
                    accK = fmaf(a4.x, wk[k4 * 4 + 0], accK);
                    accQ = fmaf(a4.x, wq[k4 * 4 + 0], accQ);
                    accK = fmaf(a4.y, wk[k4 * 4 + 1], accK);
                    accQ = fmaf(a4.y, wq[k4 * 4 + 1], accQ);
                    accK = fmaf(a4.z, wk[k4 * 4 + 2], accK);
                    accQ = fmaf(a4.z, wq[k4 * 4 + 2], accQ);
                    accK = fmaf(a4.w, wk[k4 * 4 + 3], accK);
                    accQ = fmaf(a4.w, wq[k4 * 4 + 3], accQ);
                }
                const int bb = batch[n];
                K_out[(size_t)n * F_OUTC + j] = accK + UK[(size_t)bb * F_OUTC + j];
                Q_out[(size_t)n * F_OUTC + j] = accQ + UQ[(size_t)bb * F_OUTC + j];
            }
        }
    }
}

// ---------------------------------------------------------------------------
// Launch
// ---------------------------------------------------------------------------
extern "C" void kernel_launch(void* const* d_in, const int* in_sizes, int n_in,
                              void* d_out, int out_size, void* d_ws, size_t ws_size,
                              hipStream_t stream) {
    const float* x         = (const float*)d_in[0];
    const int*   edge_idx  = (const int*)  d_in[1];
    const float* edge_attr = (const float*)d_in[2];
    const float* u         = (const float*)d_in[3];
    const int*   batch     = (const int*)  d_in[4];
    const float* W_K       = (const float*)d_in[5];
    const float* b_K       = (const float*)d_in[6];
    const float* W_Q       = (const float*)d_in[7];
    const float* b_Q       = (const float*)d_in[8];

    const int N = in_sizes[0] / F_XC;       // 100000
    const int E = in_sizes[1] / 2;          // 3200000

    const int* src = edge_idx;
    const int* dst = edge_idx + E;

    float* K_out = (float*)d_out;
    float* Q_out = K_out + (size_t)N * F_OUTC;

    const int BSZ = (N + NBUCK - 1) / NBUCK;   // 782 nodes per coarse bucket

    // workspace: recs [E u2] | agg∪recsA [max(N*64*4, E*8)] | hist [N] |
    //   cursors [N] | bucketCnt [NBUCK] | bucketOff [NBUCK+1] | gcurA [NBUCK]
    //   | UK | UQ | Wp [16K shorts]
    size_t aggA_bytes  = (size_t)N * F_XC * sizeof(float);
    size_t recsA_bytes = (size_t)E * sizeof(uint2);
    size_t unionb = aggA_bytes > recsA_bytes ? aggA_bytes : recsA_bytes;
    size_t need = (size_t)E * sizeof(uint2)
                + unionb
                + 2 * (size_t)N * sizeof(int)
                + (size_t)(3 * NBUCK + 1) * sizeof(int)
                + 2 * (size_t)B_GLOB * F_OUTC * sizeof(float)
                + (size_t)16384 * sizeof(short);

    if (ws_size >= need) {
        uint2* recs      = (uint2*)d_ws;
        char*  unionp    = (char*)(recs + (size_t)E);
        uint2* recsA     = (uint2*)unionp;          // alias: pass A/B scratch
        float* agg       = (float*)unionp;          // alias: live after partB
        int*   hist      = (int*)(unionp + unionb);
        int*   cursors   = hist + N;
        int*   bucketCnt = cursors + N;
        int*   bucketOff = bucketCnt + NBUCK;
        int*   gcurA     = bucketOff + NBUCK + 1;
        float* UK        = (float*)(gcurA + NBUCK);
        float* UQ        = UK + (size_t)B_GLOB * F_OUTC;
        short* Wp        = (short*)(UQ + (size_t)B_GLOB * F_OUTC);

        hipMemsetAsync(bucketCnt, 0, (size_t)NBUCK * sizeof(int), stream);

        bucket_hist<<<(E + 4095) / 4096, 256, 0, stream>>>(dst, bucketCnt, E, BSZ);
        bucket_scan<<<1, NBUCK, 0, stream>>>(bucketCnt, bucketOff, gcurA);
        partA_kernel<<<(E + 4095) / 4096, 256, 0, stream>>>(src, dst, edge_attr,
                                                            gcurA, recsA, E, BSZ);
        partB_fused<<<NBUCK, 1024, 0, stream>>>(recsA, bucketOff, recs,
                                                hist, cursors, N, BSZ);
        csr_accum<<<(N + 3) / 4, 256, 0, stream>>>(recs, cursors, hist, x, agg, N);
        global_proj_kernel<<<B_GLOB, 128, 0, stream>>>(u, W_K, b_K, W_Q, b_Q, UK, UQ);
        pack_w_kernel<<<8, 256, 0, stream>>>(W_K, W_Q, Wp);

        const int nch  = (N + 15) / 16;
        const int nblk = (nch + 3) / 4;
        out_mfma<<<nblk, 256, 0, stream>>>(agg, batch, Wp, UK, UQ,
                                           K_out, Q_out, N);
    } else {
        float* agg = (float*)d_ws;
        float* UK  = agg + (size_t)N * F_XC;
        float* UQ  = UK + (size_t)B_GLOB * F_OUTC;
        hipMemsetAsync(agg, 0, (size_t)N * F_XC * sizeof(float), stream);
        scatter_kernel<<<(E + 3) / 4, 256, 0, stream>>>(src, dst, edge_attr, x, agg, E);
        global_proj_kernel<<<B_GLOB, 128, 0, stream>>>(u, W_K, b_K, W_Q, b_Q, UK, UQ);
        out_csr<<<(N + 127) / 128, 256, 0, stream>>>(agg, batch, W_K, W_Q, UK, UQ,
                                                     K_out, Q_out, N);
    }
}